// Round 3
// baseline (907.646 us; speedup 1.0000x reference)
//
#include <hip/hip_runtime.h>
#include <math.h>

// Problem constants (from setup_inputs)
#define N_NODES 4096
#define BATCH   32
#define D_EMB   10
#define CIN     2
#define COUT    64
#define CI      66          // CIN + COUT
#define KSUP    3
#define NCOLS   2112        // BATCH * CI
#define NPAD    2176        // NCOLS padded (n-layout row stride)
#define LDT     4096        // t-layout row stride (m contiguous)

// MFMA-transform constants
// R15 ki-relayout: ki = k*72 + i (i<66 real). Sections at 0/72/144 halves ->
// every section base is 16B-aligned -> ds_write_b128 staging. Row stride 232
// (conflict-safe, proven) unchanged; [216,232) zero-padded on BOTH sides.
#define KSEC    72          // per-support section stride (halves)
#define KI_REAL 216         // 3*KSEC (padded k-extent actually used by 7 ksteps<=224)
#define KILD    232         // LDS row stride (>=224 for 7 ksteps; 232%32=8 -> conflict-safe)
#define OCH     (32 * KILD)    // 7424: entries per 32-output chunk
#define WROW_G  (128 * KILD)   // 29696 gate W entries per node
#define WROW_U  (64 * KILD)    // 14848 update W entries per node
#define WGT2_R  (WROW_G + WROW_U)  // 44544 ncols in the packed pool

typedef _Float16 half_t;
typedef __attribute__((ext_vector_type(8))) _Float16 f16x8;
typedef __attribute__((ext_vector_type(4))) _Float16 f16x4;
typedef __attribute__((ext_vector_type(2))) _Float16 f16x2;
typedef __attribute__((ext_vector_type(4))) float f32x4;

union u32h2 { unsigned u; f16x2 h; };

struct __attribute__((packed, aligned(4))) uint4_u4 { uint4 v; };
__device__ __forceinline__ f16x8 loadu8h(const half_t* p) {
  union { uint4 u; f16x8 h; } r;
  r.u = ((const uint4_u4*)p)->v;   // 4B-aligned 16B load (gfx950 handles it)
  return r.h;
}

__device__ __forceinline__ float fast_sigmoid(float x) { return 1.f / (1.f + __expf(-x)); }
__device__ __forceinline__ float fast_tanh(float x) { return 1.f - 2.f / (__expf(2.f * x) + 1.f); }

__device__ __forceinline__ void gld_lds16(const half_t* g, half_t* l) {
  __builtin_amdgcn_global_load_lds(
      (const __attribute__((address_space(1))) void*)g,
      (__attribute__((address_space(3))) void*)l, 16, 0, 0);
}

// ---------------------------------------------------------------------------
// P[n,m] = softmax_m(relu(E[n,:].E[m,:])) stored directly as fp16.
// ---------------------------------------------------------------------------
__global__ __launch_bounds__(256) void k_softmax_p(const float* __restrict__ E,
                                                   half_t* __restrict__ Pb) {
  const int n = blockIdx.x;
  const int tid = threadIdx.x;
  __shared__ float En[D_EMB];
  __shared__ float ms[256], ss[256];
  if (tid < D_EMB) En[tid] = E[n * D_EMB + tid];
  __syncthreads();
  float en[D_EMB];
#pragma unroll
  for (int d = 0; d < D_EMB; ++d) en[d] = En[d];

  float m = -1e30f, s = 0.f;
  for (int c = tid; c < N_NODES; c += 256) {
    const float* Ec = E + c * D_EMB;
    float v = 0.f;
#pragma unroll
    for (int d = 0; d < D_EMB; ++d) v += en[d] * Ec[d];
    v = fmaxf(v, 0.f);
    if (v > m) { s *= __expf(m - v); m = v; }
    s += __expf(v - m);
  }
  ms[tid] = m; ss[tid] = s;
  __syncthreads();
  for (int off = 128; off > 0; off >>= 1) {
    if (tid < off) {
      float m2 = ms[tid + off], s2 = ss[tid + off];
      float m1 = ms[tid], s1 = ss[tid];
      float mm = fmaxf(m1, m2);
      ms[tid] = mm;
      ss[tid] = s1 * __expf(m1 - mm) + s2 * __expf(m2 - mm);
    }
    __syncthreads();
  }
  const float M = ms[0];
  const float inv = 1.f / ss[0];
  half_t* Pr = Pb + (size_t)n * N_NODES;
  for (int c = tid; c < N_NODES; c += 256) {
    const float* Ec = E + c * D_EMB;
    float v = 0.f;
#pragma unroll
    for (int d = 0; d < D_EMB; ++d) v += en[d] * Ec[d];
    v = fmaxf(v, 0.f);
    Pr[c] = (half_t)(__expf(v - M) * inv);
  }
}

// ---------------------------------------------------------------------------
// Build V0 in both layouts (+ X part of Cb in both layouts), fp16.
// ---------------------------------------------------------------------------
__global__ __launch_bounds__(256) void k_build_v0(const float* __restrict__ X,
                                                  const float* __restrict__ H,
                                                  half_t* __restrict__ Vt,
                                                  half_t* __restrict__ Vn,
                                                  half_t* __restrict__ Cbt,
                                                  half_t* __restrict__ Cbn) {
  size_t idx = (size_t)blockIdx.x * 256 + threadIdx.x;
  if (idx >= (size_t)N_NODES * NCOLS) return;
  const int m = (int)(idx / NCOLS);
  const int col = (int)(idx % NCOLS);
  const int b = col / CI;
  const int c = col % CI;
  float v;
  if (c < CIN) v = X[((size_t)b * N_NODES + m) * CIN + c];
  else         v = H[((size_t)b * N_NODES + m) * COUT + (c - CIN)];
  const half_t h = (half_t)v;
  Vn[(size_t)m * NPAD + col] = h;
  Vt[(size_t)col * LDT + m] = h;
  if (c < CIN) {
    Cbn[(size_t)m * NPAD + col] = h;
    Cbt[(size_t)col * LDT + m] = h;
  }
}

// ---------------------------------------------------------------------------
// fp16 MFMA NT-GEMM: C[m][n] = sum_k A[m][k] * Bt[n][k]
// R16: tile 128x64 -> grid 33x32 = 1056 blocks (N=2112=33*64 exactly, no pad
// columns computed). 4.125 blocks/CU, 36KB LDS -> 4 blocks/CU co-resident =
// 16 waves/CU (was 2.125 blocks -> grid-starved, the R0-R2 119us plateau).
// Granules of 16 rows x 32 k (512 halves): A g0..7, B g8..11; wave w stages
// {w, w+4, 8+w} (3 gld_lds16). R13 in-granule swizzle + R14 depth-2
// counted-vmcnt pipeline kept (vmcnt(3) now: 3 loads/stage).
// ---------------------------------------------------------------------------
__device__ __forceinline__ void gemm_compute_tile(const half_t* __restrict__ Lb,
                                                  int wm, int wn, int fofs,
                                                  f32x4 (&acc)[4][2]) {
  f16x8 a[4], b[2];
#pragma unroll
  for (int i = 0; i < 4; ++i)
    a[i] = *(const f16x8*)&Lb[((wm >> 4) + i) * 512 + fofs];
#pragma unroll
  for (int j = 0; j < 2; ++j)
    b[j] = *(const f16x8*)&Lb[(8 + (wn >> 4) + j) * 512 + fofs];
  __builtin_amdgcn_s_setprio(1);
#pragma unroll
  for (int i = 0; i < 4; ++i)
#pragma unroll
    for (int j = 0; j < 2; ++j)
      acc[i][j] = __builtin_amdgcn_mfma_f32_16x16x32_f16(a[i], b[j], acc[i][j], 0, 0, 0);
  __builtin_amdgcn_s_setprio(0);
}

__global__ __launch_bounds__(256) void k_gemm_f16(const half_t* __restrict__ A,
                                                  const half_t* __restrict__ Bt,
                                                  half_t* __restrict__ Cn,
                                                  half_t* __restrict__ Ct) {
  __shared__ half_t LB[3][6144];   // [buf][ A g0..7 | B g8..11 ] (512 halves/granule)
  const int tid = threadIdx.x;
  const int lane = tid & 63;
  const int wave = tid >> 6;

  // XCD-aware bijective swizzle: 1056 = 8 * 132; each XCD gets 132 contiguous
  // tiles = 4 A-row-panels (4 MB = one XCD L2).
  int flat = blockIdx.y * 33 + blockIdx.x;
  flat = (flat & 7) * 132 + (flat >> 3);
  const int bx = flat % 33;
  const int by = flat / 33;

  const int wm = (wave & 1) * 64;    // 2 waves across M
  const int wn = (wave >> 1) * 32;   // 2 waves across N
  const int rb = by * 128;
  const int cb = bx * 64;

  // swizzled staging (R13): lane s -> (row s>>2, kgroup perm)
  const int srow = lane >> 2;
  const int skg = (((lane & 3) + ((lane >> 3) & 3)) & 3) * 8;
  const half_t* ga0 = A + (size_t)(rb + wave * 16 + srow) * N_NODES + skg;   // granule wave
  const half_t* ga1 = ga0 + (size_t)64 * N_NODES;                            // granule wave+4
  const half_t* gb0 = Bt + (size_t)(cb + wave * 16 + srow) * LDT + skg;      // granule 8+wave
  const int lA0 = wave * 512;
  const int lA1 = (wave + 4) * 512;
  const int lB0 = (8 + wave) * 512;

  const int fr = lane & 15;
  const int fg = lane >> 4;          // kgroup 0..3
  // fragment (row fr, kgroup fg) -> chunk 4*fr + ((fg - (fr>>1)) & 3)
  const int fofs = (4 * fr + ((fg - (fr >> 1)) & 3)) * 8;

  f32x4 acc[4][2] = {};

#define STAGE_T(buf, kk) do { half_t* Lp = LB[(buf)]; \
    gld_lds16(ga0 + (kk), Lp + lA0); gld_lds16(ga1 + (kk), Lp + lA1); \
    gld_lds16(gb0 + (kk), Lp + lB0); } while (0)

  // prologue: tiles 0,1 in flight (6 outstanding VMEM ops/wave)
  STAGE_T(0, 0);
  STAGE_T(1, 32);

  // main loop: tiles 0..125, 3x unrolled for static buffer indices.
  // Invariant at body for tile T: outstanding = stages {T, T+1} (6 loads).
  for (int t = 0; t < 126; t += 3) {
    asm volatile("s_waitcnt vmcnt(3)\n\ts_barrier" ::: "memory");
    STAGE_T(2, (t + 2) * 32);
    gemm_compute_tile(LB[0], wm, wn, fofs, acc);

    asm volatile("s_waitcnt vmcnt(3)\n\ts_barrier" ::: "memory");
    STAGE_T(0, (t + 3) * 32);
    gemm_compute_tile(LB[1], wm, wn, fofs, acc);

    asm volatile("s_waitcnt vmcnt(3)\n\ts_barrier" ::: "memory");
    STAGE_T(1, (t + 4) * 32);
    gemm_compute_tile(LB[2], wm, wn, fofs, acc);
  }
  // tail: tiles 126 (buf 0) and 127 (buf 1), no more staging
  asm volatile("s_waitcnt vmcnt(3)\n\ts_barrier" ::: "memory");
  gemm_compute_tile(LB[0], wm, wn, fofs, acc);
  asm volatile("s_waitcnt vmcnt(0)\n\ts_barrier" ::: "memory");
  gemm_compute_tile(LB[1], wm, wn, fofs, acc);
#undef STAGE_T

  const int en = lane & 15;
  const int em = (lane >> 4) * 4;
#pragma unroll
  for (int i = 0; i < 4; ++i) {
#pragma unroll
    for (int j = 0; j < 2; ++j) {
      const int m0 = rb + wm + i * 16 + em;
      const int n = cb + wn + j * 16 + en;
      half_t h0 = (half_t)acc[i][j][0];
      half_t h1 = (half_t)acc[i][j][1];
      half_t h2 = (half_t)acc[i][j][2];
      half_t h3 = (half_t)acc[i][j][3];
      if (Ct) {
        f16x4 t4 = {h0, h1, h2, h3};
        *(f16x4*)&Ct[(size_t)n * LDT + m0] = t4;
      }
      Cn[(size_t)(m0 + 0) * NPAD + n] = h0;
      Cn[(size_t)(m0 + 1) * NPAD + n] = h1;
      Cn[(size_t)(m0 + 2) * NPAD + n] = h2;
      Cn[(size_t)(m0 + 3) * NPAD + n] = h3;
    }
  }
}

// ---------------------------------------------------------------------------
// WT2: d-pair-packed fp16 pool, L2-resident. R15: ki = k*KSEC + i layout,
// pads (i in [66,72) and ki in [216,232)) are zero.
// ---------------------------------------------------------------------------
__global__ __launch_bounds__(256) void k_wgt2(const float* __restrict__ Wg,
                                              const float* __restrict__ Wu,
                                              unsigned* __restrict__ WT2) {
  const int r = blockIdx.x * 256 + threadIdx.x;
  if (r >= WGT2_R) return;
  const float* pool;
  int o, ki, ostr;
  if (r < WROW_G) { o = r / KILD; ki = r % KILD; pool = Wg; ostr = 128; }
  else { int r2 = r - WROW_G; o = r2 / KILD; ki = r2 % KILD; pool = Wu; ostr = 64; }
  const int k = ki / KSEC;
  const int i = ki - k * KSEC;
#pragma unroll
  for (int dp = 0; dp < 5; ++dp) {
    u32h2 v; v.h = f16x2{(half_t)0.f, (half_t)0.f};
    if (ki < KI_REAL && i < CI) {
      v.h[0] = (half_t)pool[(((size_t)(2 * dp) * KSUP + k) * CI + i) * ostr + o];
      v.h[1] = (half_t)pool[(((size_t)(2 * dp + 1) * KSUP + k) * CI + i) * ostr + o];
    }
    WT2[(size_t)dp * WGT2_R + r] = v.u;
  }
}

// ---------------------------------------------------------------------------
// Shared helper: stage xg for one node into LDS (rows b=0..31).
// R15: fully vectorized — per (b, octet): 3 unaligned-16B global loads +
// 3 aligned ds_write_b128 (sections at 0/72/144 halves). No per-element div.
// ---------------------------------------------------------------------------
__device__ __forceinline__ void stage_xg(const half_t* __restrict__ v0r,
                                         const half_t* __restrict__ g1r,
                                         const half_t* __restrict__ g2r,
                                         half_t* __restrict__ xg, int tid, int nthr) {
  for (int w = tid; w < 32 * 9; w += nthr) {
    const int b = w / 9;
    const int oct = w - b * 9;
    half_t* row = xg + b * KILD;
    const half_t* pv = v0r + b * CI;
    const half_t* pg1 = g1r + b * CI;
    const half_t* pg2 = g2r + b * CI;
    if (oct < 8) {
      const f16x8 v0 = loadu8h(pv + oct * 8);
      const f16x8 g1 = loadu8h(pg1 + oct * 8);
      const f16x8 g2 = loadu8h(pg2 + oct * 8);
      const f16x8 x2 = g2 + g2 - v0;
      *(f16x8*)&row[oct * 8] = v0;
      *(f16x8*)&row[KSEC + oct * 8] = g1;
      *(f16x8*)&row[2 * KSEC + oct * 8] = x2;
    } else {
      // tail i=64,65 (+ zero pad i=66..71)
      u32h2 tv, tg1, tg2;
      tv.u = *(const unsigned*)(pv + 64);
      tg1.u = *(const unsigned*)(pg1 + 64);
      tg2.u = *(const unsigned*)(pg2 + 64);
      f16x8 v0 = {}, g1 = {}, x2 = {};
      v0[0] = tv.h[0]; v0[1] = tv.h[1];
      g1[0] = tg1.h[0]; g1[1] = tg1.h[1];
      x2[0] = tg2.h[0] + tg2.h[0] - tv.h[0];
      x2[1] = tg2.h[1] + tg2.h[1] - tv.h[1];
      *(f16x8*)&row[64] = v0;
      *(f16x8*)&row[KSEC + 64] = g1;
      *(f16x8*)&row[2 * KSEC + 64] = x2;
    }
  }
  // zero row pad [216, 232)
  for (int w = tid; w < 32 * 2; w += nthr) {
    const f16x8 z = {};
    *(f16x8*)&xg[(w >> 1) * KILD + KI_REAL + (w & 1) * 8] = z;
  }
}

// ---------------------------------------------------------------------------
// Gate transform: block = 2 nodes, 512 threads (R15: 8 waves = node x ot x
// batch-half -> 16 waves/CU, doubles latency hiding of the W-transform loop).
// 4 output-chunks of 32 time-multiplexed; WT2 octets read once per node-PAIR.
// ---------------------------------------------------------------------------
__global__ __launch_bounds__(512) void k_gate_t(const half_t* __restrict__ Vn,
                                                const half_t* __restrict__ G1n,
                                                const half_t* __restrict__ G2n,
                                                const unsigned* __restrict__ WT2,
                                                const float* __restrict__ E,
                                                const float* __restrict__ bg,
                                                const float* __restrict__ H,
                                                half_t* __restrict__ Cbn,
                                                half_t* __restrict__ Cbt,
                                                half_t* __restrict__ Rb) {
  const int n0 = blockIdx.x * 2;
  const int tid = threadIdx.x;
  const int lane = tid & 63;
  const int wave = tid >> 6;
  __shared__ half_t Wl[2][OCH];
  __shared__ half_t xg[2][OCH];
  __shared__ float biasl[2][128];

  f16x2 e2p0[5], e2p1[5];
#pragma unroll
  for (int dp = 0; dp < 5; ++dp) {
    e2p0[dp][0] = (half_t)E[n0 * D_EMB + 2 * dp];
    e2p0[dp][1] = (half_t)E[n0 * D_EMB + 2 * dp + 1];
    e2p1[dp][0] = (half_t)E[(n0 + 1) * D_EMB + 2 * dp];
    e2p1[dp][1] = (half_t)E[(n0 + 1) * D_EMB + 2 * dp + 1];
  }

  if (tid < 256) {
    const int nn = tid >> 7;
    const int o = tid & 127;
    float s = 0.f;
#pragma unroll
    for (int d = 0; d < D_EMB; ++d) s += E[(n0 + nn) * D_EMB + d] * bg[d * 128 + o];
    biasl[nn][o] = s;
  }
  stage_xg(Vn + (size_t)n0 * NPAD, G1n + (size_t)n0 * NPAD, G2n + (size_t)n0 * NPAD, xg[0], tid, 512);
  stage_xg(Vn + (size_t)(n0 + 1) * NPAD, G1n + (size_t)(n0 + 1) * NPAD, G2n + (size_t)(n0 + 1) * NPAD, xg[1], tid, 512);

  const int fr = lane & 15;
  const int fk = (lane >> 4) * 8;
  const int en = lane & 15;
  const int em = (lane >> 4) * 4;
  const int node = wave & 1;
  const int ot = (wave >> 1) & 1;
  const int bh = wave >> 2;          // batch half (b rows 0-15 / 16-31)
  const int nn = n0 + node;

#pragma unroll
  for (int p = 0; p < 4; ++p) {
    if (p > 0) __syncthreads();
    for (int base = tid * 8; base < OCH; base += 4096) {
      float a0[8] = {}, a1[8] = {};
#pragma unroll
      for (int dp = 0; dp < 5; ++dp) {
        const unsigned* wrow = WT2 + (size_t)dp * WGT2_R + p * OCH + base;
        uint4 wa = *(const uint4*)wrow;
        uint4 wb = *(const uint4*)(wrow + 4);
        u32h2 c0, c1, c2, c3;
        c0.u = wa.x; c1.u = wa.y; c2.u = wa.z; c3.u = wa.w;
        a0[0] = __builtin_amdgcn_fdot2(c0.h, e2p0[dp], a0[0], false);
        a0[1] = __builtin_amdgcn_fdot2(c1.h, e2p0[dp], a0[1], false);
        a0[2] = __builtin_amdgcn_fdot2(c2.h, e2p0[dp], a0[2], false);
        a0[3] = __builtin_amdgcn_fdot2(c3.h, e2p0[dp], a0[3], false);
        a1[0] = __builtin_amdgcn_fdot2(c0.h, e2p1[dp], a1[0], false);
        a1[1] = __builtin_amdgcn_fdot2(c1.h, e2p1[dp], a1[1], false);
        a1[2] = __builtin_amdgcn_fdot2(c2.h, e2p1[dp], a1[2], false);
        a1[3] = __builtin_amdgcn_fdot2(c3.h, e2p1[dp], a1[3], false);
        c0.u = wb.x; c1.u = wb.y; c2.u = wb.z; c3.u = wb.w;
        a0[4] = __builtin_amdgcn_fdot2(c0.h, e2p0[dp], a0[4], false);
        a0[5] = __builtin_amdgcn_fdot2(c1.h, e2p0[dp], a0[5], false);
        a0[6] = __builtin_amdgcn_fdot2(c2.h, e2p0[dp], a0[6], false);
        a0[7] = __builtin_amdgcn_fdot2(c3.h, e2p0[dp], a0[7], false);
        a1[4] = __builtin_amdgcn_fdot2(c0.h, e2p1[dp], a1[4], false);
        a1[5] = __builtin_amdgcn_fdot2(c1.h, e2p1[dp], a1[5], false);
        a1[6] = __builtin_amdgcn_fdot2(c2.h, e2p1[dp], a1[6], false);
        a1[7] = __builtin_amdgcn_fdot2(c3.h, e2p1[dp], a1[7], false);
      }
      f16x8 w0, w1;
#pragma unroll
      for (int e = 0; e < 8; ++e) { w0[e] = (half_t)a0[e]; w1[e] = (half_t)a1[e]; }
      *(f16x8*)&Wl[0][base] = w0;
      *(f16x8*)&Wl[1][base] = w1;
    }
    __syncthreads();

    f32x4 acc2 = {};
#pragma unroll
    for (int ks = 0; ks < 7; ++ks) {
      const f16x8 a0 = *(const f16x8*)&xg[node][(bh * 16 + fr) * KILD + ks * 32 + fk];
      const f16x8 b0 = *(const f16x8*)&Wl[node][(ot * 16 + fr) * KILD + ks * 32 + fk];
      acc2 = __builtin_amdgcn_mfma_f32_16x16x32_f16(a0, b0, acc2, 0, 0, 0);
    }
    const int o_g = p * 32 + ot * 16 + en;
    const float bo = biasl[node][o_g];
#pragma unroll
    for (int r = 0; r < 4; ++r) {
      const int b = bh * 16 + em + r;
      const float s = fast_sigmoid(acc2[r] + bo);
      if (p < 2) {
        const float hv = H[((size_t)b * N_NODES + nn) * COUT + o_g];
        const half_t z = (half_t)(s * hv);
        const int c0 = b * CI + CIN + o_g;
        Cbn[(size_t)nn * NPAD + c0] = z;
        Cbt[(size_t)c0 * LDT + nn] = z;
      } else {
        Rb[((size_t)b * N_NODES + nn) * COUT + (o_g - 64)] = (half_t)s;
      }
    }
  }
}

// ---------------------------------------------------------------------------
// Update transform: block = 2 nodes, 512 threads, 2 output-chunks of 32.
// ---------------------------------------------------------------------------
__global__ __launch_bounds__(512) void k_update_t(const half_t* __restrict__ Cbn,
                                                  const half_t* __restrict__ G1n,
                                                  const half_t* __restrict__ G2n,
                                                  const unsigned* __restrict__ WT2,
                                                  const float* __restrict__ E,
                                                  const float* __restrict__ bu,
                                                  const float* __restrict__ H,
                                                  const half_t* __restrict__ Rb,
                                                  float* __restrict__ Out) {
  const int n0 = blockIdx.x * 2;
  const int tid = threadIdx.x;
  const int lane = tid & 63;
  const int wave = tid >> 6;
  __shared__ half_t Wl[2][OCH];
  __shared__ half_t xg[2][OCH];
  __shared__ float biasl[2][64];

  f16x2 e2p0[5], e2p1[5];
#pragma unroll
  for (int dp = 0; dp < 5; ++dp) {
    e2p0[dp][0] = (half_t)E[n0 * D_EMB + 2 * dp];
    e2p0[dp][1] = (half_t)E[n0 * D_EMB + 2 * dp + 1];
    e2p1[dp][0] = (half_t)E[(n0 + 1) * D_EMB + 2 * dp];
    e2p1[dp][1] = (half_t)E[(n0 + 1) * D_EMB + 2 * dp + 1];
  }

  if (tid < 128) {
    const int nn = tid >> 6;
    const int o = tid & 63;
    float s = 0.f;
#pragma unroll
    for (int d = 0; d < D_EMB; ++d) s += E[(n0 + nn) * D_EMB + d] * bu[d * COUT + o];
    biasl[nn][o] = s;
  }
  stage_xg(Cbn + (size_t)n0 * NPAD, G1n + (size_t)n0 * NPAD, G2n + (size_t)n0 * NPAD, xg[0], tid, 512);
  stage_xg(Cbn + (size_t)(n0 + 1) * NPAD, G1n + (size_t)(n0 + 1) * NPAD, G2n + (size_t)(n0 + 1) * NPAD, xg[1], tid, 512);

  const int fr = lane & 15;
  const int fk = (lane >> 4) * 8;
  const int en = lane & 15;
  const int em = (lane >> 4) * 4;
  const int node = wave & 1;
  const int ot = (wave >> 1) & 1;
  const int bh = wave >> 2;
  const int nn = n0 + node;

#pragma unroll
  for (int p = 0; p < 2; ++p) {
    if (p > 0) __syncthreads();
    for (int base = tid * 8; base < OCH; base += 4096) {
      float a0[8] = {}, a1[8] = {};
#pragma unroll
      for (int dp = 0; dp < 5; ++dp) {
        const unsigned* wrow = WT2 + (size_t)dp * WGT2_R + WROW_G + p * OCH + base;
        uint4 wa = *(const uint4*)wrow;
        uint4 wb = *(const uint4*)(wrow + 4);
        u32h2 c0, c1, c2, c3;
        c0.u = wa.x; c1.u = wa.y; c2.u = wa.z; c3.u = wa.w;
        a0[0] = __builtin_amdgcn_fdot2(c0.h, e2p0[dp], a0[0], false);
        a0[1] = __builtin_amdgcn_fdot2(c1.h, e2p0[dp], a0[1], false);
        a0[2] = __builtin_amdgcn_fdot2(c2.h, e2p0[dp], a0[2], false);
        a0[3] = __builtin_amdgcn_fdot2(c3.h, e2p0[dp], a0[3], false);
        a1[0] = __builtin_amdgcn_fdot2(c0.h, e2p1[dp], a1[0], false);
        a1[1] = __builtin_amdgcn_fdot2(c1.h, e2p1[dp], a1[1], false);
        a1[2] = __builtin_amdgcn_fdot2(c2.h, e2p1[dp], a1[2], false);
        a1[3] = __builtin_amdgcn_fdot2(c3.h, e2p1[dp], a1[3], false);
        c0.u = wb.x; c1.u = wb.y; c2.u = wb.z; c3.u = wb.w;
        a0[4] = __builtin_amdgcn_fdot2(c0.h, e2p0[dp], a0[4], false);
        a0[5] = __builtin_amdgcn_fdot2(c1.h, e2p0[dp], a0[5], false);
        a0[6] = __builtin_amdgcn_fdot2(c2.h, e2p0[dp], a0[6], false);
        a0[7] = __builtin_amdgcn_fdot2(c3.h, e2p0[dp], a0[7], false);
        a1[4] = __builtin_amdgcn_fdot2(c0.h, e2p1[dp], a1[4], false);
        a1[5] = __builtin_amdgcn_fdot2(c1.h, e2p1[dp], a1[5], false);
        a1[6] = __builtin_amdgcn_fdot2(c2.h, e2p1[dp], a1[6], false);
        a1[7] = __builtin_amdgcn_fdot2(c3.h, e2p1[dp], a1[7], false);
      }
      f16x8 w0, w1;
#pragma unroll
      for (int e = 0; e < 8; ++e) { w0[e] = (half_t)a0[e]; w1[e] = (half_t)a1[e]; }
      *(f16x8*)&Wl[0][base] = w0;
      *(f16x8*)&Wl[1][base] = w1;
    }
    __syncthreads();

    f32x4 acc2 = {};
#pragma unroll
    for (int ks = 0; ks < 7; ++ks) {
      const f16x8 a0 = *(const f16x8*)&xg[node][(bh * 16 + fr) * KILD + ks * 32 + fk];
      const f16x8 b0 = *(const f16x8*)&Wl[node][(ot * 16 + fr) * KILD + ks * 32 + fk];
      acc2 = __builtin_amdgcn_mfma_f32_16x16x32_f16(a0, b0, acc2, 0, 0, 0);
    }
    const int o = p * 32 + ot * 16 + en;
    const float bo = biasl[node][o];
#pragma unroll
    for (int r = 0; r < 4; ++r) {
      const int b = bh * 16 + em + r;
      const float hc = fast_tanh(acc2[r] + bo);
      const size_t base = ((size_t)b * N_NODES + nn) * COUT + o;
      const float hv = H[base];
      const float rr = (float)Rb[base];
      Out[base] = rr * hv + (1.f - rr) * hc;
    }
  }
}

// ---------------------------------------------------------------------------
extern "C" void kernel_launch(void* const* d_in, const int* in_sizes, int n_in,
                              void* d_out, int out_size, void* d_ws, size_t ws_size,
                              hipStream_t stream) {
  const float* X  = (const float*)d_in[0];
  const float* H  = (const float*)d_in[1];
  const float* E  = (const float*)d_in[2];
  const float* Wg = (const float*)d_in[3];
  const float* bg = (const float*)d_in[4];
  const float* Wu = (const float*)d_in[5];
  const float* bu = (const float*)d_in[6];
  float* out = (float*)d_out;

  const size_t SZ_P = (size_t)N_NODES * N_NODES;
  const size_t SZ_M = (size_t)NPAD * LDT;
  half_t* Pb  = (half_t*)d_ws;
  half_t* Vt  = Pb + SZ_P;
  half_t* Vn  = Vt + SZ_M;
  half_t* G1t = Vn + SZ_M;
  half_t* G1n = G1t + SZ_M;
  half_t* G2n = G1n + SZ_M;
  half_t* Cbt = G2n + SZ_M;
  half_t* Cbn = Cbt + SZ_M;
  half_t* Rb  = Cbn + SZ_M;
  unsigned* WT2 = (unsigned*)(Rb + (size_t)BATCH * N_NODES * COUT);

  // 1. adjacency + inputs + packed pool
  k_softmax_p<<<N_NODES, 256, 0, stream>>>(E, Pb);
  {
    const size_t tot = (size_t)N_NODES * NCOLS;
    k_build_v0<<<(int)((tot + 255) / 256), 256, 0, stream>>>(X, H, Vt, Vn, Cbt, Cbn);
  }
  k_wgt2<<<(WGT2_R + 255) / 256, 256, 0, stream>>>(Wg, Wu, WT2);

  dim3 gg(33, 32);   // R16: 128x64 tiles, 1056 blocks (no pad columns)
  // 2. gate propagation + transform
  k_gemm_f16<<<gg, 256, 0, stream>>>(Pb, Vt, G1n, G1t);
  k_gemm_f16<<<gg, 256, 0, stream>>>(Pb, G1t, G2n, nullptr);
  k_gate_t<<<N_NODES / 2, 512, 0, stream>>>(Vn, G1n, G2n, WT2, E, bg, H, Cbn, Cbt, Rb);
  // 3. update propagation + transform + output
  k_gemm_f16<<<gg, 256, 0, stream>>>(Pb, Cbt, G1n, G1t);
  k_gemm_f16<<<gg, 256, 0, stream>>>(Pb, G1t, G2n, nullptr);
  k_update_t<<<N_NODES / 2, 512, 0, stream>>>(Cbn, G1n, G2n, WT2, E, bu, H, Rb, out);
}

// Round 4
// 812.094 us; speedup vs baseline: 1.1177x; 1.1177x over previous
//
#include <hip/hip_runtime.h>
#include <math.h>

// Problem constants (from setup_inputs)
#define N_NODES 4096
#define BATCH   32
#define D_EMB   10
#define CIN     2
#define COUT    64
#define CI      66          // CIN + COUT
#define KSUP    3
#define NCOLS   2112        // BATCH * CI
#define NPAD    2176        // NCOLS padded (n-layout row stride)
#define LDT     4096        // t-layout row stride (m contiguous)

// MFMA-transform constants (R15 ki-relayout, proven)
#define KSEC    72          // per-support section stride (halves)
#define KI_REAL 216         // 3*KSEC
#define KILD    232         // LDS row stride (conflict-safe)
#define OCH     (32 * KILD)
#define WROW_G  (128 * KILD)
#define WROW_U  (64 * KILD)
#define WGT2_R  (WROW_G + WROW_U)

typedef _Float16 half_t;
typedef __attribute__((ext_vector_type(8))) _Float16 f16x8;
typedef __attribute__((ext_vector_type(4))) _Float16 f16x4;
typedef __attribute__((ext_vector_type(2))) _Float16 f16x2;
typedef __attribute__((ext_vector_type(4))) float f32x4;

union u32h2 { unsigned u; f16x2 h; };

struct __attribute__((packed, aligned(4))) uint4_u4 { uint4 v; };
__device__ __forceinline__ f16x8 loadu8h(const half_t* p) {
  union { uint4 u; f16x8 h; } r;
  r.u = ((const uint4_u4*)p)->v;
  return r.h;
}

__device__ __forceinline__ float fast_sigmoid(float x) { return 1.f / (1.f + __expf(-x)); }
__device__ __forceinline__ float fast_tanh(float x) { return 1.f - 2.f / (__expf(2.f * x) + 1.f); }

__device__ __forceinline__ void gld_lds16(const half_t* g, half_t* l) {
  __builtin_amdgcn_global_load_lds(
      (const __attribute__((address_space(1))) void*)g,
      (__attribute__((address_space(3))) void*)l, 16, 0, 0);
}

// ---------------------------------------------------------------------------
// P[n,m] = softmax_m(relu(E[n,:].E[m,:])) stored directly as fp16.
// ---------------------------------------------------------------------------
__global__ __launch_bounds__(256) void k_softmax_p(const float* __restrict__ E,
                                                   half_t* __restrict__ Pb) {
  const int n = blockIdx.x;
  const int tid = threadIdx.x;
  __shared__ float En[D_EMB];
  __shared__ float ms[256], ss[256];
  if (tid < D_EMB) En[tid] = E[n * D_EMB + tid];
  __syncthreads();
  float en[D_EMB];
#pragma unroll
  for (int d = 0; d < D_EMB; ++d) en[d] = En[d];

  float m = -1e30f, s = 0.f;
  for (int c = tid; c < N_NODES; c += 256) {
    const float* Ec = E + c * D_EMB;
    float v = 0.f;
#pragma unroll
    for (int d = 0; d < D_EMB; ++d) v += en[d] * Ec[d];
    v = fmaxf(v, 0.f);
    if (v > m) { s *= __expf(m - v); m = v; }
    s += __expf(v - m);
  }
  ms[tid] = m; ss[tid] = s;
  __syncthreads();
  for (int off = 128; off > 0; off >>= 1) {
    if (tid < off) {
      float m2 = ms[tid + off], s2 = ss[tid + off];
      float m1 = ms[tid], s1 = ss[tid];
      float mm = fmaxf(m1, m2);
      ms[tid] = mm;
      ss[tid] = s1 * __expf(m1 - mm) + s2 * __expf(m2 - mm);
    }
    __syncthreads();
  }
  const float M = ms[0];
  const float inv = 1.f / ss[0];
  half_t* Pr = Pb + (size_t)n * N_NODES;
  for (int c = tid; c < N_NODES; c += 256) {
    const float* Ec = E + c * D_EMB;
    float v = 0.f;
#pragma unroll
    for (int d = 0; d < D_EMB; ++d) v += en[d] * Ec[d];
    v = fmaxf(v, 0.f);
    Pr[c] = (half_t)(__expf(v - M) * inv);
  }
}

// ---------------------------------------------------------------------------
// Build V0 in both layouts (+ X part of Cb in both layouts), fp16.
// ---------------------------------------------------------------------------
__global__ __launch_bounds__(256) void k_build_v0(const float* __restrict__ X,
                                                  const float* __restrict__ H,
                                                  half_t* __restrict__ Vt,
                                                  half_t* __restrict__ Vn,
                                                  half_t* __restrict__ Cbt,
                                                  half_t* __restrict__ Cbn) {
  size_t idx = (size_t)blockIdx.x * 256 + threadIdx.x;
  if (idx >= (size_t)N_NODES * NCOLS) return;
  const int m = (int)(idx / NCOLS);
  const int col = (int)(idx % NCOLS);
  const int b = col / CI;
  const int c = col % CI;
  float v;
  if (c < CIN) v = X[((size_t)b * N_NODES + m) * CIN + c];
  else         v = H[((size_t)b * N_NODES + m) * COUT + (c - CIN)];
  const half_t h = (half_t)v;
  Vn[(size_t)m * NPAD + col] = h;
  Vt[(size_t)col * LDT + m] = h;
  if (c < CIN) {
    Cbn[(size_t)m * NPAD + col] = h;
    Cbt[(size_t)col * LDT + m] = h;
  }
}

// ---------------------------------------------------------------------------
// Shared GEMM compute tile: 16 MFMA on a staged 128x32 A / 128x32 B tile.
// (R13 fragment swizzle; R2-proven.)
// ---------------------------------------------------------------------------
__device__ __forceinline__ void gemm_compute_tile(const half_t* __restrict__ Lb,
                                                  int wm, int wn, int fofs,
                                                  f32x4 (&acc)[4][4]) {
  const half_t* As_ = Lb;
  const half_t* Bs_ = Lb + 4096;
  f16x8 a[4], b[4];
#pragma unroll
  for (int i = 0; i < 4; ++i)
    a[i] = *(const f16x8*)&As_[((wm >> 4) + i) * 512 + fofs];
#pragma unroll
  for (int j = 0; j < 4; ++j)
    b[j] = *(const f16x8*)&Bs_[((wn >> 4) + j) * 512 + fofs];
  __builtin_amdgcn_s_setprio(1);
#pragma unroll
  for (int i = 0; i < 4; ++i)
#pragma unroll
    for (int j = 0; j < 4; ++j)
      acc[i][j] = __builtin_amdgcn_mfma_f32_16x16x32_f16(a[i], b[j], acc[i][j], 0, 0, 0);
  __builtin_amdgcn_s_setprio(0);
}

// ---------------------------------------------------------------------------
// R17: K-split GEMM. 128x128 tile (R2 AI), grid 17x32x2 = 1088 blocks
// (4.25/CU, capacity 3 at 48KB LDS -> solid 12 waves/CU, no 2-generation
// tail). Each block does K-half h, writes fp32 partials. R14 depth-2
// counted-vmcnt pipeline kept (64 K-steps).
// ---------------------------------------------------------------------------
__global__ __launch_bounds__(256) void k_gemm_ks(const half_t* __restrict__ A,
                                                 const half_t* __restrict__ Bt,
                                                 float* __restrict__ Pw) {
  __shared__ half_t LB[3][8192];
  const int tid = threadIdx.x;
  const int lane = tid & 63;
  const int wave = tid >> 6;

  // XCD swizzle: 1088 = 8*136; XCD 0-3 get h=0 band, 4-7 get h=1.
  int flat = blockIdx.z * 544 + blockIdx.y * 17 + blockIdx.x;
  flat = (flat & 7) * 136 + (flat >> 3);
  const int h = flat / 544;
  const int rem = flat - h * 544;
  const int bx = rem % 17;
  const int by = rem / 17;
  const int k0 = h * 2048;

  const int wm = (wave >> 1) * 64;
  const int wn = (wave & 1) * 64;
  const int rb = by * 128;
  const int cb = bx * 128;

  const int srow = lane >> 2;
  const int skg = (((lane & 3) + ((lane >> 3) & 3)) & 3) * 8;
  const half_t* ga0 = A + (size_t)(rb + wave * 32 + srow) * N_NODES + k0 + skg;
  const half_t* ga1 = ga0 + (size_t)16 * N_NODES;
  const half_t* gb0 = Bt + (size_t)(cb + wave * 32 + srow) * LDT + k0 + skg;
  const half_t* gb1 = gb0 + (size_t)16 * LDT;
  const int lA0 = wave * 1024;
  const int lA1 = lA0 + 512;
  const int lB0 = 4096 + wave * 1024;
  const int lB1 = lB0 + 512;

  const int fr = lane & 15;
  const int fg = lane >> 4;
  const int fofs = (4 * fr + ((fg - (fr >> 1)) & 3)) * 8;

  f32x4 acc[4][4] = {};

#define STAGE_K(buf, kk) do { half_t* Lp = LB[(buf)]; \
    gld_lds16(ga0 + (kk), Lp + lA0); gld_lds16(ga1 + (kk), Lp + lA1); \
    gld_lds16(gb0 + (kk), Lp + lB0); gld_lds16(gb1 + (kk), Lp + lB1); } while (0)

  // 64 K-steps. prologue: tiles 0,1 in flight.
  STAGE_K(0, 0);
  STAGE_K(1, 32);
  for (int t = 0; t < 60; t += 3) {
    asm volatile("s_waitcnt vmcnt(4)\n\ts_barrier" ::: "memory");
    STAGE_K(2, (t + 2) * 32);
    gemm_compute_tile(LB[0], wm, wn, fofs, acc);

    asm volatile("s_waitcnt vmcnt(4)\n\ts_barrier" ::: "memory");
    STAGE_K(0, (t + 3) * 32);
    gemm_compute_tile(LB[1], wm, wn, fofs, acc);

    asm volatile("s_waitcnt vmcnt(4)\n\ts_barrier" ::: "memory");
    STAGE_K(1, (t + 4) * 32);
    gemm_compute_tile(LB[2], wm, wn, fofs, acc);
  }
  // t=60 (buf0, stage 62->buf2), t=61 (buf1, stage 63->buf0)
  asm volatile("s_waitcnt vmcnt(4)\n\ts_barrier" ::: "memory");
  STAGE_K(2, 62 * 32);
  gemm_compute_tile(LB[0], wm, wn, fofs, acc);
  asm volatile("s_waitcnt vmcnt(4)\n\ts_barrier" ::: "memory");
  STAGE_K(0, 63 * 32);
  gemm_compute_tile(LB[1], wm, wn, fofs, acc);
  // t=62 (buf2), t=63 (buf0)
  asm volatile("s_waitcnt vmcnt(4)\n\ts_barrier" ::: "memory");
  gemm_compute_tile(LB[2], wm, wn, fofs, acc);
  asm volatile("s_waitcnt vmcnt(0)\n\ts_barrier" ::: "memory");
  gemm_compute_tile(LB[0], wm, wn, fofs, acc);
#undef STAGE_K

  float* Pq = Pw + (size_t)h * ((size_t)N_NODES * NPAD);
  const int en = lane & 15;
  const int em = (lane >> 4) * 4;
#pragma unroll
  for (int i = 0; i < 4; ++i) {
#pragma unroll
    for (int j = 0; j < 4; ++j) {
      const int m0 = rb + wm + i * 16 + em;
      const int n = cb + wn + j * 16 + en;
      Pq[(size_t)(m0 + 0) * NPAD + n] = acc[i][j][0];
      Pq[(size_t)(m0 + 1) * NPAD + n] = acc[i][j][1];
      Pq[(size_t)(m0 + 2) * NPAD + n] = acc[i][j][2];
      Pq[(size_t)(m0 + 3) * NPAD + n] = acc[i][j][3];
    }
  }
}

// ---------------------------------------------------------------------------
// R17: reduce two fp32 K-half partials -> fp16 n-layout (+ optional t-layout
// via LDS 64x64 tile transpose; both global writes coalesced).
// ---------------------------------------------------------------------------
__global__ __launch_bounds__(256) void k_red(const float* __restrict__ P0,
                                             const float* __restrict__ P1,
                                             half_t* __restrict__ Cn,
                                             half_t* __restrict__ Ct) {
  __shared__ half_t T[64][69];
  const int tid = threadIdx.x;
  const int nb = blockIdx.x * 64;
  const int mb = blockIdx.y * 64;
  const int c4 = (tid & 15) * 4;
  const int r0 = tid >> 4;   // 0..15
#pragma unroll
  for (int it = 0; it < 4; ++it) {
    const int r = r0 + it * 16;
    const size_t off = (size_t)(mb + r) * NPAD + nb + c4;
    const float4 a = *(const float4*)&P0[off];
    const float4 b = *(const float4*)&P1[off];
    const half_t v0 = (half_t)(a.x + b.x);
    const half_t v1 = (half_t)(a.y + b.y);
    const half_t v2 = (half_t)(a.z + b.z);
    const half_t v3 = (half_t)(a.w + b.w);
    f16x4 v = {v0, v1, v2, v3};
    *(f16x4*)&Cn[off] = v;     // same stride NPAD
    if (Ct) {
      T[r][c4 + 0] = v0;
      T[r][c4 + 1] = v1;
      T[r][c4 + 2] = v2;
      T[r][c4 + 3] = v3;
    }
  }
  if (!Ct) return;
  __syncthreads();
#pragma unroll
  for (int it = 0; it < 4; ++it) {
    const int n2 = r0 + it * 16;
    const int m4 = c4;
    f16x4 v = {T[m4 + 0][n2], T[m4 + 1][n2], T[m4 + 2][n2], T[m4 + 3][n2]};
    *(f16x4*)&Ct[(size_t)(nb + n2) * LDT + mb + m4] = v;
  }
}

// ---------------------------------------------------------------------------
// Fallback full-K GEMM (R2-proven, 119.8us) used when workspace is too small
// for the K-split partials.
// ---------------------------------------------------------------------------
__global__ __launch_bounds__(256) void k_gemm_f16(const half_t* __restrict__ A,
                                                  const half_t* __restrict__ Bt,
                                                  half_t* __restrict__ Cn,
                                                  half_t* __restrict__ Ct) {
  __shared__ half_t LB[3][8192];
  const int tid = threadIdx.x;
  const int lane = tid & 63;
  const int wave = tid >> 6;

  int flat = blockIdx.y * 17 + blockIdx.x;
  flat = (flat & 7) * 68 + (flat >> 3);
  const int bx = flat % 17;
  const int by = flat / 17;

  const int wm = (wave >> 1) * 64;
  const int wn = (wave & 1) * 64;
  const int rb = by * 128;
  const int cb = bx * 128;

  const int srow = lane >> 2;
  const int skg = (((lane & 3) + ((lane >> 3) & 3)) & 3) * 8;
  const half_t* ga0 = A + (size_t)(rb + wave * 32 + srow) * N_NODES + skg;
  const half_t* ga1 = ga0 + (size_t)16 * N_NODES;
  const half_t* gb0 = Bt + (size_t)(cb + wave * 32 + srow) * LDT + skg;
  const half_t* gb1 = gb0 + (size_t)16 * LDT;
  const int lA0 = wave * 1024;
  const int lA1 = lA0 + 512;
  const int lB0 = 4096 + wave * 1024;
  const int lB1 = lB0 + 512;

  const int fr = lane & 15;
  const int fg = lane >> 4;
  const int fofs = (4 * fr + ((fg - (fr >> 1)) & 3)) * 8;

  f32x4 acc[4][4] = {};

#define STAGE_T(buf, kk) do { half_t* Lp = LB[(buf)]; \
    gld_lds16(ga0 + (kk), Lp + lA0); gld_lds16(ga1 + (kk), Lp + lA1); \
    gld_lds16(gb0 + (kk), Lp + lB0); gld_lds16(gb1 + (kk), Lp + lB1); } while (0)

  STAGE_T(0, 0);
  STAGE_T(1, 32);
  for (int t = 0; t < 126; t += 3) {
    asm volatile("s_waitcnt vmcnt(4)\n\ts_barrier" ::: "memory");
    STAGE_T(2, (t + 2) * 32);
    gemm_compute_tile(LB[0], wm, wn, fofs, acc);

    asm volatile("s_waitcnt vmcnt(4)\n\ts_barrier" ::: "memory");
    STAGE_T(0, (t + 3) * 32);
    gemm_compute_tile(LB[1], wm, wn, fofs, acc);

    asm volatile("s_waitcnt vmcnt(4)\n\ts_barrier" ::: "memory");
    STAGE_T(1, (t + 4) * 32);
    gemm_compute_tile(LB[2], wm, wn, fofs, acc);
  }
  asm volatile("s_waitcnt vmcnt(4)\n\ts_barrier" ::: "memory");
  gemm_compute_tile(LB[0], wm, wn, fofs, acc);
  asm volatile("s_waitcnt vmcnt(0)\n\ts_barrier" ::: "memory");
  gemm_compute_tile(LB[1], wm, wn, fofs, acc);
#undef STAGE_T

  const int en = lane & 15;
  const int em = (lane >> 4) * 4;
#pragma unroll
  for (int i = 0; i < 4; ++i) {
#pragma unroll
    for (int j = 0; j < 4; ++j) {
      const int m0 = rb + wm + i * 16 + em;
      const int n = cb + wn + j * 16 + en;
      half_t h0 = (half_t)acc[i][j][0];
      half_t h1 = (half_t)acc[i][j][1];
      half_t h2 = (half_t)acc[i][j][2];
      half_t h3 = (half_t)acc[i][j][3];
      if (Ct) {
        f16x4 t4 = {h0, h1, h2, h3};
        *(f16x4*)&Ct[(size_t)n * LDT + m0] = t4;
      }
      Cn[(size_t)(m0 + 0) * NPAD + n] = h0;
      Cn[(size_t)(m0 + 1) * NPAD + n] = h1;
      Cn[(size_t)(m0 + 2) * NPAD + n] = h2;
      Cn[(size_t)(m0 + 3) * NPAD + n] = h3;
    }
  }
}

// ---------------------------------------------------------------------------
// WT2: d-pair-packed fp16 pool, L2-resident (R15 ki = k*KSEC + i layout).
// ---------------------------------------------------------------------------
__global__ __launch_bounds__(256) void k_wgt2(const float* __restrict__ Wg,
                                              const float* __restrict__ Wu,
                                              unsigned* __restrict__ WT2) {
  const int r = blockIdx.x * 256 + threadIdx.x;
  if (r >= WGT2_R) return;
  const float* pool;
  int o, ki, ostr;
  if (r < WROW_G) { o = r / KILD; ki = r % KILD; pool = Wg; ostr = 128; }
  else { int r2 = r - WROW_G; o = r2 / KILD; ki = r2 % KILD; pool = Wu; ostr = 64; }
  const int k = ki / KSEC;
  const int i = ki - k * KSEC;
#pragma unroll
  for (int dp = 0; dp < 5; ++dp) {
    u32h2 v; v.h = f16x2{(half_t)0.f, (half_t)0.f};
    if (ki < KI_REAL && i < CI) {
      v.h[0] = (half_t)pool[(((size_t)(2 * dp) * KSUP + k) * CI + i) * ostr + o];
      v.h[1] = (half_t)pool[(((size_t)(2 * dp + 1) * KSUP + k) * CI + i) * ostr + o];
    }
    WT2[(size_t)dp * WGT2_R + r] = v.u;
  }
}

// ---------------------------------------------------------------------------
// Stage xg for one node into LDS (R15 vectorized).
// ---------------------------------------------------------------------------
__device__ __forceinline__ void stage_xg(const half_t* __restrict__ v0r,
                                         const half_t* __restrict__ g1r,
                                         const half_t* __restrict__ g2r,
                                         half_t* __restrict__ xg, int tid, int nthr) {
  for (int w = tid; w < 32 * 9; w += nthr) {
    const int b = w / 9;
    const int oct = w - b * 9;
    half_t* row = xg + b * KILD;
    const half_t* pv = v0r + b * CI;
    const half_t* pg1 = g1r + b * CI;
    const half_t* pg2 = g2r + b * CI;
    if (oct < 8) {
      const f16x8 v0 = loadu8h(pv + oct * 8);
      const f16x8 g1 = loadu8h(pg1 + oct * 8);
      const f16x8 g2 = loadu8h(pg2 + oct * 8);
      const f16x8 x2 = g2 + g2 - v0;
      *(f16x8*)&row[oct * 8] = v0;
      *(f16x8*)&row[KSEC + oct * 8] = g1;
      *(f16x8*)&row[2 * KSEC + oct * 8] = x2;
    } else {
      u32h2 tv, tg1, tg2;
      tv.u = *(const unsigned*)(pv + 64);
      tg1.u = *(const unsigned*)(pg1 + 64);
      tg2.u = *(const unsigned*)(pg2 + 64);
      f16x8 v0 = {}, g1 = {}, x2 = {};
      v0[0] = tv.h[0]; v0[1] = tv.h[1];
      g1[0] = tg1.h[0]; g1[1] = tg1.h[1];
      x2[0] = tg2.h[0] + tg2.h[0] - tv.h[0];
      x2[1] = tg2.h[1] + tg2.h[1] - tv.h[1];
      *(f16x8*)&row[64] = v0;
      *(f16x8*)&row[KSEC + 64] = g1;
      *(f16x8*)&row[2 * KSEC + 64] = x2;
    }
  }
  for (int w = tid; w < 32 * 2; w += nthr) {
    const f16x8 z = {};
    *(f16x8*)&xg[(w >> 1) * KILD + KI_REAL + (w & 1) * 8] = z;
  }
}

// ---------------------------------------------------------------------------
// Gate transform: block = 2 nodes, 512 threads (R15-proven).
// ---------------------------------------------------------------------------
__global__ __launch_bounds__(512) void k_gate_t(const half_t* __restrict__ Vn,
                                                const half_t* __restrict__ G1n,
                                                const half_t* __restrict__ G2n,
                                                const unsigned* __restrict__ WT2,
                                                const float* __restrict__ E,
                                                const float* __restrict__ bg,
                                                const float* __restrict__ H,
                                                half_t* __restrict__ Cbn,
                                                half_t* __restrict__ Cbt,
                                                half_t* __restrict__ Rb) {
  const int n0 = blockIdx.x * 2;
  const int tid = threadIdx.x;
  const int lane = tid & 63;
  const int wave = tid >> 6;
  __shared__ half_t Wl[2][OCH];
  __shared__ half_t xg[2][OCH];
  __shared__ float biasl[2][128];

  f16x2 e2p0[5], e2p1[5];
#pragma unroll
  for (int dp = 0; dp < 5; ++dp) {
    e2p0[dp][0] = (half_t)E[n0 * D_EMB + 2 * dp];
    e2p0[dp][1] = (half_t)E[n0 * D_EMB + 2 * dp + 1];
    e2p1[dp][0] = (half_t)E[(n0 + 1) * D_EMB + 2 * dp];
    e2p1[dp][1] = (half_t)E[(n0 + 1) * D_EMB + 2 * dp + 1];
  }

  if (tid < 256) {
    const int nn = tid >> 7;
    const int o = tid & 127;
    float s = 0.f;
#pragma unroll
    for (int d = 0; d < D_EMB; ++d) s += E[(n0 + nn) * D_EMB + d] * bg[d * 128 + o];
    biasl[nn][o] = s;
  }
  stage_xg(Vn + (size_t)n0 * NPAD, G1n + (size_t)n0 * NPAD, G2n + (size_t)n0 * NPAD, xg[0], tid, 512);
  stage_xg(Vn + (size_t)(n0 + 1) * NPAD, G1n + (size_t)(n0 + 1) * NPAD, G2n + (size_t)(n0 + 1) * NPAD, xg[1], tid, 512);

  const int fr = lane & 15;
  const int fk = (lane >> 4) * 8;
  const int en = lane & 15;
  const int em = (lane >> 4) * 4;
  const int node = wave & 1;
  const int ot = (wave >> 1) & 1;
  const int bh = wave >> 2;
  const int nn = n0 + node;

#pragma unroll
  for (int p = 0; p < 4; ++p) {
    if (p > 0) __syncthreads();
    for (int base = tid * 8; base < OCH; base += 4096) {
      float a0[8] = {}, a1[8] = {};
#pragma unroll
      for (int dp = 0; dp < 5; ++dp) {
        const unsigned* wrow = WT2 + (size_t)dp * WGT2_R + p * OCH + base;
        uint4 wa = *(const uint4*)wrow;
        uint4 wb = *(const uint4*)(wrow + 4);
        u32h2 c0, c1, c2, c3;
        c0.u = wa.x; c1.u = wa.y; c2.u = wa.z; c3.u = wa.w;
        a0[0] = __builtin_amdgcn_fdot2(c0.h, e2p0[dp], a0[0], false);
        a0[1] = __builtin_amdgcn_fdot2(c1.h, e2p0[dp], a0[1], false);
        a0[2] = __builtin_amdgcn_fdot2(c2.h, e2p0[dp], a0[2], false);
        a0[3] = __builtin_amdgcn_fdot2(c3.h, e2p0[dp], a0[3], false);
        a1[0] = __builtin_amdgcn_fdot2(c0.h, e2p1[dp], a1[0], false);
        a1[1] = __builtin_amdgcn_fdot2(c1.h, e2p1[dp], a1[1], false);
        a1[2] = __builtin_amdgcn_fdot2(c2.h, e2p1[dp], a1[2], false);
        a1[3] = __builtin_amdgcn_fdot2(c3.h, e2p1[dp], a1[3], false);
        c0.u = wb.x; c1.u = wb.y; c2.u = wb.z; c3.u = wb.w;
        a0[4] = __builtin_amdgcn_fdot2(c0.h, e2p0[dp], a0[4], false);
        a0[5] = __builtin_amdgcn_fdot2(c1.h, e2p0[dp], a0[5], false);
        a0[6] = __builtin_amdgcn_fdot2(c2.h, e2p0[dp], a0[6], false);
        a0[7] = __builtin_amdgcn_fdot2(c3.h, e2p0[dp], a0[7], false);
        a1[4] = __builtin_amdgcn_fdot2(c0.h, e2p1[dp], a1[4], false);
        a1[5] = __builtin_amdgcn_fdot2(c1.h, e2p1[dp], a1[5], false);
        a1[6] = __builtin_amdgcn_fdot2(c2.h, e2p1[dp], a1[6], false);
        a1[7] = __builtin_amdgcn_fdot2(c3.h, e2p1[dp], a1[7], false);
      }
      f16x8 w0, w1;
#pragma unroll
      for (int e = 0; e < 8; ++e) { w0[e] = (half_t)a0[e]; w1[e] = (half_t)a1[e]; }
      *(f16x8*)&Wl[0][base] = w0;
      *(f16x8*)&Wl[1][base] = w1;
    }
    __syncthreads();

    f32x4 acc2 = {};
#pragma unroll
    for (int ks = 0; ks < 7; ++ks) {
      const f16x8 a0 = *(const f16x8*)&xg[node][(bh * 16 + fr) * KILD + ks * 32 + fk];
      const f16x8 b0 = *(const f16x8*)&Wl[node][(ot * 16 + fr) * KILD + ks * 32 + fk];
      acc2 = __builtin_amdgcn_mfma_f32_16x16x32_f16(a0, b0, acc2, 0, 0, 0);
    }
    const int o_g = p * 32 + ot * 16 + en;
    const float bo = biasl[node][o_g];
#pragma unroll
    for (int r = 0; r < 4; ++r) {
      const int b = bh * 16 + em + r;
      const float s = fast_sigmoid(acc2[r] + bo);
      if (p < 2) {
        const float hv = H[((size_t)b * N_NODES + nn) * COUT + o_g];
        const half_t z = (half_t)(s * hv);
        const int c0 = b * CI + CIN + o_g;
        Cbn[(size_t)nn * NPAD + c0] = z;
        Cbt[(size_t)c0 * LDT + nn] = z;
      } else {
        Rb[((size_t)b * N_NODES + nn) * COUT + (o_g - 64)] = (half_t)s;
      }
    }
  }
}

// ---------------------------------------------------------------------------
// Update transform: block = 2 nodes, 512 threads (R15-proven).
// ---------------------------------------------------------------------------
__global__ __launch_bounds__(512) void k_update_t(const half_t* __restrict__ Cbn,
                                                  const half_t* __restrict__ G1n,
                                                  const half_t* __restrict__ G2n,
                                                  const unsigned* __restrict__ WT2,
                                                  const float* __restrict__ E,
                                                  const float* __restrict__ bu,
                                                  const float* __restrict__ H,
                                                  const half_t* __restrict__ Rb,
                                                  float* __restrict__ Out) {
  const int n0 = blockIdx.x * 2;
  const int tid = threadIdx.x;
  const int lane = tid & 63;
  const int wave = tid >> 6;
  __shared__ half_t Wl[2][OCH];
  __shared__ half_t xg[2][OCH];
  __shared__ float biasl[2][64];

  f16x2 e2p0[5], e2p1[5];
#pragma unroll
  for (int dp = 0; dp < 5; ++dp) {
    e2p0[dp][0] = (half_t)E[n0 * D_EMB + 2 * dp];
    e2p0[dp][1] = (half_t)E[n0 * D_EMB + 2 * dp + 1];
    e2p1[dp][0] = (half_t)E[(n0 + 1) * D_EMB + 2 * dp];
    e2p1[dp][1] = (half_t)E[(n0 + 1) * D_EMB + 2 * dp + 1];
  }

  if (tid < 128) {
    const int nn = tid >> 6;
    const int o = tid & 63;
    float s = 0.f;
#pragma unroll
    for (int d = 0; d < D_EMB; ++d) s += E[(n0 + nn) * D_EMB + d] * bu[d * COUT + o];
    biasl[nn][o] = s;
  }
  stage_xg(Cbn + (size_t)n0 * NPAD, G1n + (size_t)n0 * NPAD, G2n + (size_t)n0 * NPAD, xg[0], tid, 512);
  stage_xg(Cbn + (size_t)(n0 + 1) * NPAD, G1n + (size_t)(n0 + 1) * NPAD, G2n + (size_t)(n0 + 1) * NPAD, xg[1], tid, 512);

  const int fr = lane & 15;
  const int fk = (lane >> 4) * 8;
  const int en = lane & 15;
  const int em = (lane >> 4) * 4;
  const int node = wave & 1;
  const int ot = (wave >> 1) & 1;
  const int bh = wave >> 2;
  const int nn = n0 + node;

#pragma unroll
  for (int p = 0; p < 2; ++p) {
    if (p > 0) __syncthreads();
    for (int base = tid * 8; base < OCH; base += 4096) {
      float a0[8] = {}, a1[8] = {};
#pragma unroll
      for (int dp = 0; dp < 5; ++dp) {
        const unsigned* wrow = WT2 + (size_t)dp * WGT2_R + WROW_G + p * OCH + base;
        uint4 wa = *(const uint4*)wrow;
        uint4 wb = *(const uint4*)(wrow + 4);
        u32h2 c0, c1, c2, c3;
        c0.u = wa.x; c1.u = wa.y; c2.u = wa.z; c3.u = wa.w;
        a0[0] = __builtin_amdgcn_fdot2(c0.h, e2p0[dp], a0[0], false);
        a0[1] = __builtin_amdgcn_fdot2(c1.h, e2p0[dp], a0[1], false);
        a0[2] = __builtin_amdgcn_fdot2(c2.h, e2p0[dp], a0[2], false);
        a0[3] = __builtin_amdgcn_fdot2(c3.h, e2p0[dp], a0[3], false);
        a1[0] = __builtin_amdgcn_fdot2(c0.h, e2p1[dp], a1[0], false);
        a1[1] = __builtin_amdgcn_fdot2(c1.h, e2p1[dp], a1[1], false);
        a1[2] = __builtin_amdgcn_fdot2(c2.h, e2p1[dp], a1[2], false);
        a1[3] = __builtin_amdgcn_fdot2(c3.h, e2p1[dp], a1[3], false);
        c0.u = wb.x; c1.u = wb.y; c2.u = wb.z; c3.u = wb.w;
        a0[4] = __builtin_amdgcn_fdot2(c0.h, e2p0[dp], a0[4], false);
        a0[5] = __builtin_amdgcn_fdot2(c1.h, e2p0[dp], a0[5], false);
        a0[6] = __builtin_amdgcn_fdot2(c2.h, e2p0[dp], a0[6], false);
        a0[7] = __builtin_amdgcn_fdot2(c3.h, e2p0[dp], a0[7], false);
        a1[4] = __builtin_amdgcn_fdot2(c0.h, e2p1[dp], a1[4], false);
        a1[5] = __builtin_amdgcn_fdot2(c1.h, e2p1[dp], a1[5], false);
        a1[6] = __builtin_amdgcn_fdot2(c2.h, e2p1[dp], a1[6], false);
        a1[7] = __builtin_amdgcn_fdot2(c3.h, e2p1[dp], a1[7], false);
      }
      f16x8 w0, w1;
#pragma unroll
      for (int e = 0; e < 8; ++e) { w0[e] = (half_t)a0[e]; w1[e] = (half_t)a1[e]; }
      *(f16x8*)&Wl[0][base] = w0;
      *(f16x8*)&Wl[1][base] = w1;
    }
    __syncthreads();

    f32x4 acc2 = {};
#pragma unroll
    for (int ks = 0; ks < 7; ++ks) {
      const f16x8 a0 = *(const f16x8*)&xg[node][(bh * 16 + fr) * KILD + ks * 32 + fk];
      const f16x8 b0 = *(const f16x8*)&Wl[node][(ot * 16 + fr) * KILD + ks * 32 + fk];
      acc2 = __builtin_amdgcn_mfma_f32_16x16x32_f16(a0, b0, acc2, 0, 0, 0);
    }
    const int o = p * 32 + ot * 16 + en;
    const float bo = biasl[node][o];
#pragma unroll
    for (int r = 0; r < 4; ++r) {
      const int b = bh * 16 + em + r;
      const float hc = fast_tanh(acc2[r] + bo);
      const size_t base = ((size_t)b * N_NODES + nn) * COUT + o;
      const float hv = H[base];
      const float rr = (float)Rb[base];
      Out[base] = rr * hv + (1.f - rr) * hc;
    }
  }
}

// ---------------------------------------------------------------------------
extern "C" void kernel_launch(void* const* d_in, const int* in_sizes, int n_in,
                              void* d_out, int out_size, void* d_ws, size_t ws_size,
                              hipStream_t stream) {
  const float* X  = (const float*)d_in[0];
  const float* H  = (const float*)d_in[1];
  const float* E  = (const float*)d_in[2];
  const float* Wg = (const float*)d_in[3];
  const float* bg = (const float*)d_in[4];
  const float* Wu = (const float*)d_in[5];
  const float* bu = (const float*)d_in[6];
  float* out = (float*)d_out;

  const size_t SZ_P = (size_t)N_NODES * N_NODES;
  const size_t SZ_M = (size_t)NPAD * LDT;
  half_t* Pb  = (half_t*)d_ws;
  half_t* Vt  = Pb + SZ_P;
  half_t* Vn  = Vt + SZ_M;
  half_t* G1t = Vn + SZ_M;
  half_t* G1n = G1t + SZ_M;
  half_t* G2n = G1n + SZ_M;
  half_t* Cbt = G2n + SZ_M;
  half_t* Cbn = Cbt + SZ_M;
  half_t* Rb  = Cbn + SZ_M;
  unsigned* WT2 = (unsigned*)(Rb + (size_t)BATCH * N_NODES * COUT);

  // K-split partials: 2 x (4096 x 2176) fp32 after WT2 (runtime ws check).
  const size_t SZC = (size_t)N_NODES * NPAD;
  size_t wt2_end = (size_t)((char*)(WT2 + 5 * (size_t)WGT2_R) - (char*)d_ws);
  size_t pofs = (wt2_end + 255) & ~(size_t)255;
  const bool split = ws_size >= pofs + 2 * SZC * sizeof(float);
  float* Pw = (float*)((char*)d_ws + pofs);

  // 1. adjacency + inputs + packed pool
  k_softmax_p<<<N_NODES, 256, 0, stream>>>(E, Pb);
  {
    const size_t tot = (size_t)N_NODES * NCOLS;
    k_build_v0<<<(int)((tot + 255) / 256), 256, 0, stream>>>(X, H, Vt, Vn, Cbt, Cbn);
  }
  k_wgt2<<<(WGT2_R + 255) / 256, 256, 0, stream>>>(Wg, Wu, WT2);

  const dim3 gk(17, 32, 2);     // K-split grid
  const dim3 gr(34, 64);        // reduce grid (64x64 tiles)
  const dim3 gg(17, 32);        // fallback full-K grid

  // 2. gate propagation + transform
  if (split) {
    k_gemm_ks<<<gk, 256, 0, stream>>>(Pb, Vt, Pw);
    k_red<<<gr, 256, 0, stream>>>(Pw, Pw + SZC, G1n, G1t);
    k_gemm_ks<<<gk, 256, 0, stream>>>(Pb, G1t, Pw);
    k_red<<<gr, 256, 0, stream>>>(Pw, Pw + SZC, G2n, nullptr);
  } else {
    k_gemm_f16<<<gg, 256, 0, stream>>>(Pb, Vt, G1n, G1t);
    k_gemm_f16<<<gg, 256, 0, stream>>>(Pb, G1t, G2n, nullptr);
  }
  k_gate_t<<<N_NODES / 2, 512, 0, stream>>>(Vn, G1n, G2n, WT2, E, bg, H, Cbn, Cbt, Rb);

  // 3. update propagation + transform + output
  if (split) {
    k_gemm_ks<<<gk, 256, 0, stream>>>(Pb, Cbt, Pw);
    k_red<<<gr, 256, 0, stream>>>(Pw, Pw + SZC, G1n, G1t);
    k_gemm_ks<<<gk, 256, 0, stream>>>(Pb, G1t, Pw);
    k_red<<<gr, 256, 0, stream>>>(Pw, Pw + SZC, G2n, nullptr);
  } else {
    k_gemm_f16<<<gg, 256, 0, stream>>>(Pb, Cbt, G1n, G1t);
    k_gemm_f16<<<gg, 256, 0, stream>>>(Pb, G1t, G2n, nullptr);
  }
  k_update_t<<<N_NODES / 2, 512, 0, stream>>>(Cbn, G1n, G2n, WT2, E, bu, H, Rb, out);
}

// Round 5
// 762.198 us; speedup vs baseline: 1.1908x; 1.0655x over previous
//
#include <hip/hip_runtime.h>
#include <math.h>

// Problem constants (from setup_inputs)
#define N_NODES 4096
#define BATCH   32
#define D_EMB   10
#define CIN     2
#define COUT    64
#define CI      66          // CIN + COUT
#define KSUP    3
#define NCOLS   2112        // BATCH * CI
#define NPAD    2176        // NCOLS padded (n-layout row stride)
#define LDT     4096        // t-layout row stride (m contiguous)

// MFMA-transform constants (R15 ki-relayout, proven)
#define KSEC    72          // per-support section stride (halves)
#define KI_REAL 216         // 3*KSEC
#define KILD    232         // LDS row stride (conflict-safe)
#define OCH     (32 * KILD)
#define WROW_G  (128 * KILD)
#define WROW_U  (64 * KILD)
#define WGT2_R  (WROW_G + WROW_U)

typedef _Float16 half_t;
typedef __attribute__((ext_vector_type(8))) _Float16 f16x8;
typedef __attribute__((ext_vector_type(4))) _Float16 f16x4;
typedef __attribute__((ext_vector_type(2))) _Float16 f16x2;
typedef __attribute__((ext_vector_type(4))) float f32x4;

union u32h2 { unsigned u; f16x2 h; };

struct __attribute__((packed, aligned(4))) uint4_u4 { uint4 v; };
__device__ __forceinline__ f16x8 loadu8h(const half_t* p) {
  union { uint4 u; f16x8 h; } r;
  r.u = ((const uint4_u4*)p)->v;
  return r.h;
}

__device__ __forceinline__ float fast_sigmoid(float x) { return 1.f / (1.f + __expf(-x)); }
__device__ __forceinline__ float fast_tanh(float x) { return 1.f - 2.f / (__expf(2.f * x) + 1.f); }

__device__ __forceinline__ void gld_lds16(const half_t* g, half_t* l) {
  __builtin_amdgcn_global_load_lds(
      (const __attribute__((address_space(1))) void*)g,
      (__attribute__((address_space(3))) void*)l, 16, 0, 0);
}

// ---------------------------------------------------------------------------
// P[n,m] = softmax_m(relu(E[n,:].E[m,:])) stored directly as fp16.
// ---------------------------------------------------------------------------
__global__ __launch_bounds__(256) void k_softmax_p(const float* __restrict__ E,
                                                   half_t* __restrict__ Pb) {
  const int n = blockIdx.x;
  const int tid = threadIdx.x;
  __shared__ float En[D_EMB];
  __shared__ float ms[256], ss[256];
  if (tid < D_EMB) En[tid] = E[n * D_EMB + tid];
  __syncthreads();
  float en[D_EMB];
#pragma unroll
  for (int d = 0; d < D_EMB; ++d) en[d] = En[d];

  float m = -1e30f, s = 0.f;
  for (int c = tid; c < N_NODES; c += 256) {
    const float* Ec = E + c * D_EMB;
    float v = 0.f;
#pragma unroll
    for (int d = 0; d < D_EMB; ++d) v += en[d] * Ec[d];
    v = fmaxf(v, 0.f);
    if (v > m) { s *= __expf(m - v); m = v; }
    s += __expf(v - m);
  }
  ms[tid] = m; ss[tid] = s;
  __syncthreads();
  for (int off = 128; off > 0; off >>= 1) {
    if (tid < off) {
      float m2 = ms[tid + off], s2 = ss[tid + off];
      float m1 = ms[tid], s1 = ss[tid];
      float mm = fmaxf(m1, m2);
      ms[tid] = mm;
      ss[tid] = s1 * __expf(m1 - mm) + s2 * __expf(m2 - mm);
    }
    __syncthreads();
  }
  const float M = ms[0];
  const float inv = 1.f / ss[0];
  half_t* Pr = Pb + (size_t)n * N_NODES;
  for (int c = tid; c < N_NODES; c += 256) {
    const float* Ec = E + c * D_EMB;
    float v = 0.f;
#pragma unroll
    for (int d = 0; d < D_EMB; ++d) v += en[d] * Ec[d];
    v = fmaxf(v, 0.f);
    Pr[c] = (half_t)(__expf(v - M) * inv);
  }
}

// ---------------------------------------------------------------------------
// Build V0 in both layouts (+ X part of Cbn), fp16. R18: Cbt X-part no longer
// written here (k_tr produces the whole Cbt after gate_t).
// ---------------------------------------------------------------------------
__global__ __launch_bounds__(256) void k_build_v0(const float* __restrict__ X,
                                                  const float* __restrict__ H,
                                                  half_t* __restrict__ Vt,
                                                  half_t* __restrict__ Vn,
                                                  half_t* __restrict__ Cbn) {
  size_t idx = (size_t)blockIdx.x * 256 + threadIdx.x;
  if (idx >= (size_t)N_NODES * NCOLS) return;
  const int m = (int)(idx / NCOLS);
  const int col = (int)(idx % NCOLS);
  const int b = col / CI;
  const int c = col % CI;
  float v;
  if (c < CIN) v = X[((size_t)b * N_NODES + m) * CIN + c];
  else         v = H[((size_t)b * N_NODES + m) * COUT + (c - CIN)];
  const half_t h = (half_t)v;
  Vn[(size_t)m * NPAD + col] = h;
  Vt[(size_t)col * LDT + m] = h;
  if (c < CIN) Cbn[(size_t)m * NPAD + col] = h;
}

// ---------------------------------------------------------------------------
// fp16 MFMA NT-GEMM: C[m][n] = sum_k A[m][k] * Bt[n][k]
// R2-proven config: 128x128 tile, grid 17x32, R13 staging swizzle, R14
// depth-2 counted-vmcnt pipeline, XCD-bijective swizzle (544 = 8*68).
// ---------------------------------------------------------------------------
__device__ __forceinline__ void gemm_compute_tile(const half_t* __restrict__ Lb,
                                                  int wm, int wn, int fofs,
                                                  f32x4 (&acc)[4][4]) {
  const half_t* As_ = Lb;
  const half_t* Bs_ = Lb + 4096;
  f16x8 a[4], b[4];
#pragma unroll
  for (int i = 0; i < 4; ++i)
    a[i] = *(const f16x8*)&As_[((wm >> 4) + i) * 512 + fofs];
#pragma unroll
  for (int j = 0; j < 4; ++j)
    b[j] = *(const f16x8*)&Bs_[((wn >> 4) + j) * 512 + fofs];
  __builtin_amdgcn_s_setprio(1);
#pragma unroll
  for (int i = 0; i < 4; ++i)
#pragma unroll
    for (int j = 0; j < 4; ++j)
      acc[i][j] = __builtin_amdgcn_mfma_f32_16x16x32_f16(a[i], b[j], acc[i][j], 0, 0, 0);
  __builtin_amdgcn_s_setprio(0);
}

__global__ __launch_bounds__(256) void k_gemm_f16(const half_t* __restrict__ A,
                                                  const half_t* __restrict__ Bt,
                                                  half_t* __restrict__ Cn,
                                                  half_t* __restrict__ Ct) {
  __shared__ half_t LB[3][8192];
  const int tid = threadIdx.x;
  const int lane = tid & 63;
  const int wave = tid >> 6;

  int flat = blockIdx.y * 17 + blockIdx.x;
  flat = (flat & 7) * 68 + (flat >> 3);
  const int bx = flat % 17;
  const int by = flat / 17;

  const int wm = (wave >> 1) * 64;
  const int wn = (wave & 1) * 64;
  const int rb = by * 128;
  const int cb = bx * 128;

  const int srow = lane >> 2;
  const int skg = (((lane & 3) + ((lane >> 3) & 3)) & 3) * 8;
  const half_t* ga0 = A + (size_t)(rb + wave * 32 + srow) * N_NODES + skg;
  const half_t* ga1 = ga0 + (size_t)16 * N_NODES;
  const half_t* gb0 = Bt + (size_t)(cb + wave * 32 + srow) * LDT + skg;
  const half_t* gb1 = gb0 + (size_t)16 * LDT;
  const int lA0 = wave * 1024;
  const int lA1 = lA0 + 512;
  const int lB0 = 4096 + wave * 1024;
  const int lB1 = lB0 + 512;

  const int fr = lane & 15;
  const int fg = lane >> 4;
  const int fofs = (4 * fr + ((fg - (fr >> 1)) & 3)) * 8;

  f32x4 acc[4][4] = {};

#define STAGE_T(buf, kk) do { half_t* Lp = LB[(buf)]; \
    gld_lds16(ga0 + (kk), Lp + lA0); gld_lds16(ga1 + (kk), Lp + lA1); \
    gld_lds16(gb0 + (kk), Lp + lB0); gld_lds16(gb1 + (kk), Lp + lB1); } while (0)

  STAGE_T(0, 0);
  STAGE_T(1, 32);
  for (int t = 0; t < 126; t += 3) {
    asm volatile("s_waitcnt vmcnt(4)\n\ts_barrier" ::: "memory");
    STAGE_T(2, (t + 2) * 32);
    gemm_compute_tile(LB[0], wm, wn, fofs, acc);

    asm volatile("s_waitcnt vmcnt(4)\n\ts_barrier" ::: "memory");
    STAGE_T(0, (t + 3) * 32);
    gemm_compute_tile(LB[1], wm, wn, fofs, acc);

    asm volatile("s_waitcnt vmcnt(4)\n\ts_barrier" ::: "memory");
    STAGE_T(1, (t + 4) * 32);
    gemm_compute_tile(LB[2], wm, wn, fofs, acc);
  }
  asm volatile("s_waitcnt vmcnt(4)\n\ts_barrier" ::: "memory");
  gemm_compute_tile(LB[0], wm, wn, fofs, acc);
  asm volatile("s_waitcnt vmcnt(0)\n\ts_barrier" ::: "memory");
  gemm_compute_tile(LB[1], wm, wn, fofs, acc);
#undef STAGE_T

  const int en = lane & 15;
  const int em = (lane >> 4) * 4;
#pragma unroll
  for (int i = 0; i < 4; ++i) {
#pragma unroll
    for (int j = 0; j < 4; ++j) {
      const int m0 = rb + wm + i * 16 + em;
      const int n = cb + wn + j * 16 + en;
      half_t h0 = (half_t)acc[i][j][0];
      half_t h1 = (half_t)acc[i][j][1];
      half_t h2 = (half_t)acc[i][j][2];
      half_t h3 = (half_t)acc[i][j][3];
      if (Ct) {
        f16x4 t4 = {h0, h1, h2, h3};
        *(f16x4*)&Ct[(size_t)n * LDT + m0] = t4;
      }
      Cn[(size_t)(m0 + 0) * NPAD + n] = h0;
      Cn[(size_t)(m0 + 1) * NPAD + n] = h1;
      Cn[(size_t)(m0 + 2) * NPAD + n] = h2;
      Cn[(size_t)(m0 + 3) * NPAD + n] = h3;
    }
  }
}

// ---------------------------------------------------------------------------
// R18: coalesced transpose Cbn (node-major) -> Cbt (col-major). 64x64 LDS
// tiles, both global sides coalesced. Replaces gate_t's 8KB-stride scattered
// Cbt stores (the 198MB WRITE_SIZE pathology).
// ---------------------------------------------------------------------------
__global__ __launch_bounds__(256) void k_tr(const half_t* __restrict__ Cbn,
                                            half_t* __restrict__ Ct) {
  __shared__ half_t T[64][69];
  const int tid = threadIdx.x;
  const int cb = blockIdx.x * 64;   // col base (0..2048)
  const int mb = blockIdx.y * 64;   // node base
  const int c4 = (tid & 15) * 4;
  const int r0 = tid >> 4;
#pragma unroll
  for (int it = 0; it < 4; ++it) {
    const int r = r0 + it * 16;
    f16x4 v = *(const f16x4*)&Cbn[(size_t)(mb + r) * NPAD + cb + c4];
    T[r][c4 + 0] = v[0];
    T[r][c4 + 1] = v[1];
    T[r][c4 + 2] = v[2];
    T[r][c4 + 3] = v[3];
  }
  __syncthreads();
#pragma unroll
  for (int it = 0; it < 4; ++it) {
    const int c2 = r0 + it * 16;     // col within tile
    const int m4 = c4;               // node within tile
    f16x4 v = {T[m4 + 0][c2], T[m4 + 1][c2], T[m4 + 2][c2], T[m4 + 3][c2]};
    *(f16x4*)&Ct[(size_t)(cb + c2) * LDT + mb + m4] = v;
  }
}

// ---------------------------------------------------------------------------
// WT2: d-pair-packed fp16 pool, L2-resident (R15 ki = k*KSEC + i layout).
// ---------------------------------------------------------------------------
__global__ __launch_bounds__(256) void k_wgt2(const float* __restrict__ Wg,
                                              const float* __restrict__ Wu,
                                              unsigned* __restrict__ WT2) {
  const int r = blockIdx.x * 256 + threadIdx.x;
  if (r >= WGT2_R) return;
  const float* pool;
  int o, ki, ostr;
  if (r < WROW_G) { o = r / KILD; ki = r % KILD; pool = Wg; ostr = 128; }
  else { int r2 = r - WROW_G; o = r2 / KILD; ki = r2 % KILD; pool = Wu; ostr = 64; }
  const int k = ki / KSEC;
  const int i = ki - k * KSEC;
#pragma unroll
  for (int dp = 0; dp < 5; ++dp) {
    u32h2 v; v.h = f16x2{(half_t)0.f, (half_t)0.f};
    if (ki < KI_REAL && i < CI) {
      v.h[0] = (half_t)pool[(((size_t)(2 * dp) * KSUP + k) * CI + i) * ostr + o];
      v.h[1] = (half_t)pool[(((size_t)(2 * dp + 1) * KSUP + k) * CI + i) * ostr + o];
    }
    WT2[(size_t)dp * WGT2_R + r] = v.u;
  }
}

// ---------------------------------------------------------------------------
// Stage xg for one node into LDS (R15 vectorized).
// ---------------------------------------------------------------------------
__device__ __forceinline__ void stage_xg(const half_t* __restrict__ v0r,
                                         const half_t* __restrict__ g1r,
                                         const half_t* __restrict__ g2r,
                                         half_t* __restrict__ xg, int tid, int nthr) {
  for (int w = tid; w < 32 * 9; w += nthr) {
    const int b = w / 9;
    const int oct = w - b * 9;
    half_t* row = xg + b * KILD;
    const half_t* pv = v0r + b * CI;
    const half_t* pg1 = g1r + b * CI;
    const half_t* pg2 = g2r + b * CI;
    if (oct < 8) {
      const f16x8 v0 = loadu8h(pv + oct * 8);
      const f16x8 g1 = loadu8h(pg1 + oct * 8);
      const f16x8 g2 = loadu8h(pg2 + oct * 8);
      const f16x8 x2 = g2 + g2 - v0;
      *(f16x8*)&row[oct * 8] = v0;
      *(f16x8*)&row[KSEC + oct * 8] = g1;
      *(f16x8*)&row[2 * KSEC + oct * 8] = x2;
    } else {
      u32h2 tv, tg1, tg2;
      tv.u = *(const unsigned*)(pv + 64);
      tg1.u = *(const unsigned*)(pg1 + 64);
      tg2.u = *(const unsigned*)(pg2 + 64);
      f16x8 v0 = {}, g1 = {}, x2 = {};
      v0[0] = tv.h[0]; v0[1] = tv.h[1];
      g1[0] = tg1.h[0]; g1[1] = tg1.h[1];
      x2[0] = tg2.h[0] + tg2.h[0] - tv.h[0];
      x2[1] = tg2.h[1] + tg2.h[1] - tv.h[1];
      *(f16x8*)&row[64] = v0;
      *(f16x8*)&row[KSEC + 64] = g1;
      *(f16x8*)&row[2 * KSEC + 64] = x2;
    }
  }
  for (int w = tid; w < 32 * 2; w += nthr) {
    const f16x8 z = {};
    *(f16x8*)&xg[(w >> 1) * KILD + KI_REAL + (w & 1) * 8] = z;
  }
}

// ---------------------------------------------------------------------------
// Gate transform: block = 2 nodes, 512 threads. R18: Cbt scatter removed
// (k_tr does the transpose); Rb stored node-major Rb[nn*2048 + b*64 + o]
// (wave-local 32B segments instead of 2B stores 256KB apart).
// ---------------------------------------------------------------------------
__global__ __launch_bounds__(512) void k_gate_t(const half_t* __restrict__ Vn,
                                                const half_t* __restrict__ G1n,
                                                const half_t* __restrict__ G2n,
                                                const unsigned* __restrict__ WT2,
                                                const float* __restrict__ E,
                                                const float* __restrict__ bg,
                                                const float* __restrict__ H,
                                                half_t* __restrict__ Cbn,
                                                half_t* __restrict__ Rb) {
  const int n0 = blockIdx.x * 2;
  const int tid = threadIdx.x;
  const int lane = tid & 63;
  const int wave = tid >> 6;
  __shared__ half_t Wl[2][OCH];
  __shared__ half_t xg[2][OCH];
  __shared__ float biasl[2][128];

  f16x2 e2p0[5], e2p1[5];
#pragma unroll
  for (int dp = 0; dp < 5; ++dp) {
    e2p0[dp][0] = (half_t)E[n0 * D_EMB + 2 * dp];
    e2p0[dp][1] = (half_t)E[n0 * D_EMB + 2 * dp + 1];
    e2p1[dp][0] = (half_t)E[(n0 + 1) * D_EMB + 2 * dp];
    e2p1[dp][1] = (half_t)E[(n0 + 1) * D_EMB + 2 * dp + 1];
  }

  if (tid < 256) {
    const int nn = tid >> 7;
    const int o = tid & 127;
    float s = 0.f;
#pragma unroll
    for (int d = 0; d < D_EMB; ++d) s += E[(n0 + nn) * D_EMB + d] * bg[d * 128 + o];
    biasl[nn][o] = s;
  }
  stage_xg(Vn + (size_t)n0 * NPAD, G1n + (size_t)n0 * NPAD, G2n + (size_t)n0 * NPAD, xg[0], tid, 512);
  stage_xg(Vn + (size_t)(n0 + 1) * NPAD, G1n + (size_t)(n0 + 1) * NPAD, G2n + (size_t)(n0 + 1) * NPAD, xg[1], tid, 512);

  const int fr = lane & 15;
  const int fk = (lane >> 4) * 8;
  const int en = lane & 15;
  const int em = (lane >> 4) * 4;
  const int node = wave & 1;
  const int ot = (wave >> 1) & 1;
  const int bh = wave >> 2;
  const int nn = n0 + node;

#pragma unroll
  for (int p = 0; p < 4; ++p) {
    if (p > 0) __syncthreads();
    for (int base = tid * 8; base < OCH; base += 4096) {
      float a0[8] = {}, a1[8] = {};
#pragma unroll
      for (int dp = 0; dp < 5; ++dp) {
        const unsigned* wrow = WT2 + (size_t)dp * WGT2_R + p * OCH + base;
        uint4 wa = *(const uint4*)wrow;
        uint4 wb = *(const uint4*)(wrow + 4);
        u32h2 c0, c1, c2, c3;
        c0.u = wa.x; c1.u = wa.y; c2.u = wa.z; c3.u = wa.w;
        a0[0] = __builtin_amdgcn_fdot2(c0.h, e2p0[dp], a0[0], false);
        a0[1] = __builtin_amdgcn_fdot2(c1.h, e2p0[dp], a0[1], false);
        a0[2] = __builtin_amdgcn_fdot2(c2.h, e2p0[dp], a0[2], false);
        a0[3] = __builtin_amdgcn_fdot2(c3.h, e2p0[dp], a0[3], false);
        a1[0] = __builtin_amdgcn_fdot2(c0.h, e2p1[dp], a1[0], false);
        a1[1] = __builtin_amdgcn_fdot2(c1.h, e2p1[dp], a1[1], false);
        a1[2] = __builtin_amdgcn_fdot2(c2.h, e2p1[dp], a1[2], false);
        a1[3] = __builtin_amdgcn_fdot2(c3.h, e2p1[dp], a1[3], false);
        c0.u = wb.x; c1.u = wb.y; c2.u = wb.z; c3.u = wb.w;
        a0[4] = __builtin_amdgcn_fdot2(c0.h, e2p0[dp], a0[4], false);
        a0[5] = __builtin_amdgcn_fdot2(c1.h, e2p0[dp], a0[5], false);
        a0[6] = __builtin_amdgcn_fdot2(c2.h, e2p0[dp], a0[6], false);
        a0[7] = __builtin_amdgcn_fdot2(c3.h, e2p0[dp], a0[7], false);
        a1[4] = __builtin_amdgcn_fdot2(c0.h, e2p1[dp], a1[4], false);
        a1[5] = __builtin_amdgcn_fdot2(c1.h, e2p1[dp], a1[5], false);
        a1[6] = __builtin_amdgcn_fdot2(c2.h, e2p1[dp], a1[6], false);
        a1[7] = __builtin_amdgcn_fdot2(c3.h, e2p1[dp], a1[7], false);
      }
      f16x8 w0, w1;
#pragma unroll
      for (int e = 0; e < 8; ++e) { w0[e] = (half_t)a0[e]; w1[e] = (half_t)a1[e]; }
      *(f16x8*)&Wl[0][base] = w0;
      *(f16x8*)&Wl[1][base] = w1;
    }
    __syncthreads();

    f32x4 acc2 = {};
#pragma unroll
    for (int ks = 0; ks < 7; ++ks) {
      const f16x8 a0 = *(const f16x8*)&xg[node][(bh * 16 + fr) * KILD + ks * 32 + fk];
      const f16x8 b0 = *(const f16x8*)&Wl[node][(ot * 16 + fr) * KILD + ks * 32 + fk];
      acc2 = __builtin_amdgcn_mfma_f32_16x16x32_f16(a0, b0, acc2, 0, 0, 0);
    }
    const int o_g = p * 32 + ot * 16 + en;
    const float bo = biasl[node][o_g];
#pragma unroll
    for (int r = 0; r < 4; ++r) {
      const int b = bh * 16 + em + r;
      const float s = fast_sigmoid(acc2[r] + bo);
      if (p < 2) {
        const float hv = H[((size_t)b * N_NODES + nn) * COUT + o_g];
        const half_t z = (half_t)(s * hv);
        Cbn[(size_t)nn * NPAD + b * CI + CIN + o_g] = z;
      } else {
        Rb[(size_t)nn * 2048 + b * COUT + (o_g - 64)] = (half_t)s;
      }
    }
  }
}

// ---------------------------------------------------------------------------
// Update transform: block = 2 nodes, 512 threads. R18: Rb read node-major.
// ---------------------------------------------------------------------------
__global__ __launch_bounds__(512) void k_update_t(const half_t* __restrict__ Cbn,
                                                  const half_t* __restrict__ G1n,
                                                  const half_t* __restrict__ G2n,
                                                  const unsigned* __restrict__ WT2,
                                                  const float* __restrict__ E,
                                                  const float* __restrict__ bu,
                                                  const float* __restrict__ H,
                                                  const half_t* __restrict__ Rb,
                                                  float* __restrict__ Out) {
  const int n0 = blockIdx.x * 2;
  const int tid = threadIdx.x;
  const int lane = tid & 63;
  const int wave = tid >> 6;
  __shared__ half_t Wl[2][OCH];
  __shared__ half_t xg[2][OCH];
  __shared__ float biasl[2][64];

  f16x2 e2p0[5], e2p1[5];
#pragma unroll
  for (int dp = 0; dp < 5; ++dp) {
    e2p0[dp][0] = (half_t)E[n0 * D_EMB + 2 * dp];
    e2p0[dp][1] = (half_t)E[n0 * D_EMB + 2 * dp + 1];
    e2p1[dp][0] = (half_t)E[(n0 + 1) * D_EMB + 2 * dp];
    e2p1[dp][1] = (half_t)E[(n0 + 1) * D_EMB + 2 * dp + 1];
  }

  if (tid < 128) {
    const int nn = tid >> 6;
    const int o = tid & 63;
    float s = 0.f;
#pragma unroll
    for (int d = 0; d < D_EMB; ++d) s += E[(n0 + nn) * D_EMB + d] * bu[d * COUT + o];
    biasl[nn][o] = s;
  }
  stage_xg(Cbn + (size_t)n0 * NPAD, G1n + (size_t)n0 * NPAD, G2n + (size_t)n0 * NPAD, xg[0], tid, 512);
  stage_xg(Cbn + (size_t)(n0 + 1) * NPAD, G1n + (size_t)(n0 + 1) * NPAD, G2n + (size_t)(n0 + 1) * NPAD, xg[1], tid, 512);

  const int fr = lane & 15;
  const int fk = (lane >> 4) * 8;
  const int en = lane & 15;
  const int em = (lane >> 4) * 4;
  const int node = wave & 1;
  const int ot = (wave >> 1) & 1;
  const int bh = wave >> 2;
  const int nn = n0 + node;

#pragma unroll
  for (int p = 0; p < 2; ++p) {
    if (p > 0) __syncthreads();
    for (int base = tid * 8; base < OCH; base += 4096) {
      float a0[8] = {}, a1[8] = {};
#pragma unroll
      for (int dp = 0; dp < 5; ++dp) {
        const unsigned* wrow = WT2 + (size_t)dp * WGT2_R + WROW_G + p * OCH + base;
        uint4 wa = *(const uint4*)wrow;
        uint4 wb = *(const uint4*)(wrow + 4);
        u32h2 c0, c1, c2, c3;
        c0.u = wa.x; c1.u = wa.y; c2.u = wa.z; c3.u = wa.w;
        a0[0] = __builtin_amdgcn_fdot2(c0.h, e2p0[dp], a0[0], false);
        a0[1] = __builtin_amdgcn_fdot2(c1.h, e2p0[dp], a0[1], false);
        a0[2] = __builtin_amdgcn_fdot2(c2.h, e2p0[dp], a0[2], false);
        a0[3] = __builtin_amdgcn_fdot2(c3.h, e2p0[dp], a0[3], false);
        a1[0] = __builtin_amdgcn_fdot2(c0.h, e2p1[dp], a1[0], false);
        a1[1] = __builtin_amdgcn_fdot2(c1.h, e2p1[dp], a1[1], false);
        a1[2] = __builtin_amdgcn_fdot2(c2.h, e2p1[dp], a1[2], false);
        a1[3] = __builtin_amdgcn_fdot2(c3.h, e2p1[dp], a1[3], false);
        c0.u = wb.x; c1.u = wb.y; c2.u = wb.z; c3.u = wb.w;
        a0[4] = __builtin_amdgcn_fdot2(c0.h, e2p0[dp], a0[4], false);
        a0[5] = __builtin_amdgcn_fdot2(c1.h, e2p0[dp], a0[5], false);
        a0[6] = __builtin_amdgcn_fdot2(c2.h, e2p0[dp], a0[6], false);
        a0[7] = __builtin_amdgcn_fdot2(c3.h, e2p0[dp], a0[7], false);
        a1[4] = __builtin_amdgcn_fdot2(c0.h, e2p1[dp], a1[4], false);
        a1[5] = __builtin_amdgcn_fdot2(c1.h, e2p1[dp], a1[5], false);
        a1[6] = __builtin_amdgcn_fdot2(c2.h, e2p1[dp], a1[6], false);
        a1[7] = __builtin_amdgcn_fdot2(c3.h, e2p1[dp], a1[7], false);
      }
      f16x8 w0, w1;
#pragma unroll
      for (int e = 0; e < 8; ++e) { w0[e] = (half_t)a0[e]; w1[e] = (half_t)a1[e]; }
      *(f16x8*)&Wl[0][base] = w0;
      *(f16x8*)&Wl[1][base] = w1;
    }
    __syncthreads();

    f32x4 acc2 = {};
#pragma unroll
    for (int ks = 0; ks < 7; ++ks) {
      const f16x8 a0 = *(const f16x8*)&xg[node][(bh * 16 + fr) * KILD + ks * 32 + fk];
      const f16x8 b0 = *(const f16x8*)&Wl[node][(ot * 16 + fr) * KILD + ks * 32 + fk];
      acc2 = __builtin_amdgcn_mfma_f32_16x16x32_f16(a0, b0, acc2, 0, 0, 0);
    }
    const int o = p * 32 + ot * 16 + en;
    const float bo = biasl[node][o];
#pragma unroll
    for (int r = 0; r < 4; ++r) {
      const int b = bh * 16 + em + r;
      const float hc = fast_tanh(acc2[r] + bo);
      const float hv = H[((size_t)b * N_NODES + nn) * COUT + o];
      const float rr = (float)Rb[(size_t)nn * 2048 + b * COUT + o];
      Out[((size_t)b * N_NODES + nn) * COUT + o] = rr * hv + (1.f - rr) * hc;
    }
  }
}

// ---------------------------------------------------------------------------
extern "C" void kernel_launch(void* const* d_in, const int* in_sizes, int n_in,
                              void* d_out, int out_size, void* d_ws, size_t ws_size,
                              hipStream_t stream) {
  const float* X  = (const float*)d_in[0];
  const float* H  = (const float*)d_in[1];
  const float* E  = (const float*)d_in[2];
  const float* Wg = (const float*)d_in[3];
  const float* bg = (const float*)d_in[4];
  const float* Wu = (const float*)d_in[5];
  const float* bu = (const float*)d_in[6];
  float* out = (float*)d_out;

  const size_t SZ_P = (size_t)N_NODES * N_NODES;
  const size_t SZ_M = (size_t)NPAD * LDT;
  half_t* Pb  = (half_t*)d_ws;
  half_t* Vt  = Pb + SZ_P;
  half_t* Vn  = Vt + SZ_M;
  half_t* G1t = Vn + SZ_M;
  half_t* G1n = G1t + SZ_M;
  half_t* G2n = G1n + SZ_M;
  half_t* Cbt = G2n + SZ_M;
  half_t* Cbn = Cbt + SZ_M;
  half_t* Rb  = Cbn + SZ_M;
  unsigned* WT2 = (unsigned*)(Rb + (size_t)BATCH * N_NODES * COUT);

  // 1. adjacency + inputs + packed pool
  k_softmax_p<<<N_NODES, 256, 0, stream>>>(E, Pb);
  {
    const size_t tot = (size_t)N_NODES * NCOLS;
    k_build_v0<<<(int)((tot + 255) / 256), 256, 0, stream>>>(X, H, Vt, Vn, Cbn);
  }
  k_wgt2<<<(WGT2_R + 255) / 256, 256, 0, stream>>>(Wg, Wu, WT2);

  const dim3 gg(17, 32);       // full-K GEMM grid (R2-proven)
  const dim3 gt(33, 64);       // transpose grid (64x64 tiles over 2112x4096)

  // 2. gate propagation + transform
  k_gemm_f16<<<gg, 256, 0, stream>>>(Pb, Vt, G1n, G1t);
  k_gemm_f16<<<gg, 256, 0, stream>>>(Pb, G1t, G2n, nullptr);
  k_gate_t<<<N_NODES / 2, 512, 0, stream>>>(Vn, G1n, G2n, WT2, E, bg, H, Cbn, Rb);
  k_tr<<<gt, 256, 0, stream>>>(Cbn, Cbt);

  // 3. update propagation + transform + output
  k_gemm_f16<<<gg, 256, 0, stream>>>(Pb, Cbt, G1n, G1t);
  k_gemm_f16<<<gg, 256, 0, stream>>>(Pb, G1t, G2n, nullptr);
  k_update_t<<<N_NODES / 2, 512, 0, stream>>>(Cbn, G1n, G2n, WT2, E, bu, H, Rb, out);
}

// Round 6
// 728.039 us; speedup vs baseline: 1.2467x; 1.0469x over previous
//
#include <hip/hip_runtime.h>
#include <math.h>

// Problem constants (from setup_inputs)
#define N_NODES 4096
#define BATCH   32
#define D_EMB   10
#define CIN     2
#define COUT    64
#define CI      66          // CIN + COUT
#define KSUP    3
#define NCOLS   2112        // BATCH * CI
#define NPAD    2176        // NCOLS padded (n-layout row stride)
#define LDT     4096        // t-layout row stride (m contiguous)

// MFMA-transform constants (R15 ki-relayout, proven)
#define KSEC    72          // per-support section stride (halves)
#define KI_REAL 216         // 3*KSEC
#define KILD    232         // LDS row stride (conflict-safe)
#define OCH     (32 * KILD)
#define WROW_G  (128 * KILD)
#define WROW_U  (64 * KILD)
#define WGT2_R  (WROW_G + WROW_U)

typedef _Float16 half_t;
typedef __attribute__((ext_vector_type(8))) _Float16 f16x8;
typedef __attribute__((ext_vector_type(4))) _Float16 f16x4;
typedef __attribute__((ext_vector_type(2))) _Float16 f16x2;
typedef __attribute__((ext_vector_type(4))) float f32x4;

union u32h2 { unsigned u; f16x2 h; };

struct __attribute__((packed, aligned(4))) uint4_u4 { uint4 v; };
__device__ __forceinline__ f16x8 loadu8h(const half_t* p) {
  union { uint4 u; f16x8 h; } r;
  r.u = ((const uint4_u4*)p)->v;
  return r.h;
}

__device__ __forceinline__ float fast_sigmoid(float x) { return 1.f / (1.f + __expf(-x)); }
__device__ __forceinline__ float fast_tanh(float x) { return 1.f - 2.f / (__expf(2.f * x) + 1.f); }

__device__ __forceinline__ void gld_lds16(const half_t* g, half_t* l) {
  __builtin_amdgcn_global_load_lds(
      (const __attribute__((address_space(1))) void*)g,
      (__attribute__((address_space(3))) void*)l, 16, 0, 0);
}

// ---------------------------------------------------------------------------
// P[n,m] = softmax_m(relu(E[n,:].E[m,:])) stored directly as fp16.
// R19: per-thread register cache of the 16 dot products (4096/256) -> the
// second E.E pass is eliminated; pass 2 is exp+store only.
// ---------------------------------------------------------------------------
__global__ __launch_bounds__(256) void k_softmax_p(const float* __restrict__ E,
                                                   half_t* __restrict__ Pb) {
  const int n = blockIdx.x;
  const int tid = threadIdx.x;
  __shared__ float En[D_EMB];
  __shared__ float ms[256], ss[256];
  if (tid < D_EMB) En[tid] = E[n * D_EMB + tid];
  __syncthreads();
  float en[D_EMB];
#pragma unroll
  for (int d = 0; d < D_EMB; ++d) en[d] = En[d];

  float val[16];
  float m = -1e30f, s = 0.f;
#pragma unroll
  for (int it = 0; it < 16; ++it) {
    const int c = tid + it * 256;
    const float* Ec = E + c * D_EMB;
    float v = 0.f;
#pragma unroll
    for (int d = 0; d < D_EMB; ++d) v += en[d] * Ec[d];
    v = fmaxf(v, 0.f);
    val[it] = v;
    if (v > m) { s *= __expf(m - v); m = v; }
    s += __expf(v - m);
  }
  ms[tid] = m; ss[tid] = s;
  __syncthreads();
  for (int off = 128; off > 0; off >>= 1) {
    if (tid < off) {
      float m2 = ms[tid + off], s2 = ss[tid + off];
      float m1 = ms[tid], s1 = ss[tid];
      float mm = fmaxf(m1, m2);
      ms[tid] = mm;
      ss[tid] = s1 * __expf(m1 - mm) + s2 * __expf(m2 - mm);
    }
    __syncthreads();
  }
  const float M = ms[0];
  const float inv = 1.f / ss[0];
  half_t* Pr = Pb + (size_t)n * N_NODES;
#pragma unroll
  for (int it = 0; it < 16; ++it)
    Pr[tid + it * 256] = (half_t)(__expf(val[it] - M) * inv);
}

// ---------------------------------------------------------------------------
// Build V0 in both layouts (+ X part of Cbn), fp16.
// ---------------------------------------------------------------------------
__global__ __launch_bounds__(256) void k_build_v0(const float* __restrict__ X,
                                                  const float* __restrict__ H,
                                                  half_t* __restrict__ Vt,
                                                  half_t* __restrict__ Vn,
                                                  half_t* __restrict__ Cbn) {
  size_t idx = (size_t)blockIdx.x * 256 + threadIdx.x;
  if (idx >= (size_t)N_NODES * NCOLS) return;
  const int m = (int)(idx / NCOLS);
  const int col = (int)(idx % NCOLS);
  const int b = col / CI;
  const int c = col % CI;
  float v;
  if (c < CIN) v = X[((size_t)b * N_NODES + m) * CIN + c];
  else         v = H[((size_t)b * N_NODES + m) * COUT + (c - CIN)];
  const half_t h = (half_t)v;
  Vn[(size_t)m * NPAD + col] = h;
  Vt[(size_t)col * LDT + m] = h;
  if (c < CIN) Cbn[(size_t)m * NPAD + col] = h;
}

// ---------------------------------------------------------------------------
// fp16 MFMA NT-GEMM: C[m][n] = sum_k A[m][k] * Bt[n][k]
// 128x128 tile, grid 17x32, R13 staging swizzle, XCD-bijective swizzle.
// R19: depth-3 pipeline, 4 LDS buffers (64 KB, m132-proven size).
// Steady state: 12 loads outstanding (3 stages x 4), s_waitcnt vmcnt(8)
// waits only for the oldest stage -> L3/HBM latency amortized over 3
// K-steps of compute (R0/R2/R4 showed depth-2 leaves latency exposed;
// TLP scaling was refuted by R3/R4).
// ---------------------------------------------------------------------------
__device__ __forceinline__ void gemm_compute_tile(const half_t* __restrict__ Lb,
                                                  int wm, int wn, int fofs,
                                                  f32x4 (&acc)[4][4]) {
  const half_t* As_ = Lb;
  const half_t* Bs_ = Lb + 4096;
  f16x8 a[4], b[4];
#pragma unroll
  for (int i = 0; i < 4; ++i)
    a[i] = *(const f16x8*)&As_[((wm >> 4) + i) * 512 + fofs];
#pragma unroll
  for (int j = 0; j < 4; ++j)
    b[j] = *(const f16x8*)&Bs_[((wn >> 4) + j) * 512 + fofs];
  __builtin_amdgcn_s_setprio(1);
#pragma unroll
  for (int i = 0; i < 4; ++i)
#pragma unroll
    for (int j = 0; j < 4; ++j)
      acc[i][j] = __builtin_amdgcn_mfma_f32_16x16x32_f16(a[i], b[j], acc[i][j], 0, 0, 0);
  __builtin_amdgcn_s_setprio(0);
}

__global__ __launch_bounds__(256) void k_gemm_f16(const half_t* __restrict__ A,
                                                  const half_t* __restrict__ Bt,
                                                  half_t* __restrict__ Cn,
                                                  half_t* __restrict__ Ct) {
  __shared__ half_t LB[4][8192];   // 64 KB: 4 buffers (depth-3 ring)
  const int tid = threadIdx.x;
  const int lane = tid & 63;
  const int wave = tid >> 6;

  int flat = blockIdx.y * 17 + blockIdx.x;
  flat = (flat & 7) * 68 + (flat >> 3);
  const int bx = flat % 17;
  const int by = flat / 17;

  const int wm = (wave >> 1) * 64;
  const int wn = (wave & 1) * 64;
  const int rb = by * 128;
  const int cb = bx * 128;

  const int srow = lane >> 2;
  const int skg = (((lane & 3) + ((lane >> 3) & 3)) & 3) * 8;
  const half_t* ga0 = A + (size_t)(rb + wave * 32 + srow) * N_NODES + skg;
  const half_t* ga1 = ga0 + (size_t)16 * N_NODES;
  const half_t* gb0 = Bt + (size_t)(cb + wave * 32 + srow) * LDT + skg;
  const half_t* gb1 = gb0 + (size_t)16 * LDT;
  const int lA0 = wave * 1024;
  const int lA1 = lA0 + 512;
  const int lB0 = 4096 + wave * 1024;
  const int lB1 = lB0 + 512;

  const int fr = lane & 15;
  const int fg = lane >> 4;
  const int fofs = (4 * fr + ((fg - (fr >> 1)) & 3)) * 8;

  f32x4 acc[4][4] = {};

#define STAGE_T(buf, kk) do { half_t* Lp = LB[(buf)]; \
    gld_lds16(ga0 + (kk), Lp + lA0); gld_lds16(ga1 + (kk), Lp + lA1); \
    gld_lds16(gb0 + (kk), Lp + lB0); gld_lds16(gb1 + (kk), Lp + lB1); } while (0)

  // prologue: stages 0,1,2 in flight (12 outstanding VMEM ops/wave)
  STAGE_T(0, 0);
  STAGE_T(1, 32);
  STAGE_T(2, 64);

  // main loop: tiles 0..123 (124 = 31*4 iterations, 4x unrolled for static
  // buffer indices). Invariant at body for tile T: outstanding stages
  // {T, T+1, T+2} (12 loads); vmcnt(8) -> stage T complete. Stage of
  // buf[(T+3)%4] == buf[(T-1)%4] is issued AFTER the barrier (WAR-safe:
  // every wave finished compute(T-1) before its barrier of step T).
  for (int t = 0; t < 124; t += 4) {
    asm volatile("s_waitcnt vmcnt(8)\n\ts_barrier" ::: "memory");
    STAGE_T(3, (t + 3) * 32);
    gemm_compute_tile(LB[0], wm, wn, fofs, acc);

    asm volatile("s_waitcnt vmcnt(8)\n\ts_barrier" ::: "memory");
    STAGE_T(0, (t + 4) * 32);
    gemm_compute_tile(LB[1], wm, wn, fofs, acc);

    asm volatile("s_waitcnt vmcnt(8)\n\ts_barrier" ::: "memory");
    STAGE_T(1, (t + 5) * 32);
    gemm_compute_tile(LB[2], wm, wn, fofs, acc);

    asm volatile("s_waitcnt vmcnt(8)\n\ts_barrier" ::: "memory");
    STAGE_T(2, (t + 6) * 32);
    gemm_compute_tile(LB[3], wm, wn, fofs, acc);
  }
  // tail: tiles 124..127 (last group staged 123..126; stage 127 here)
  asm volatile("s_waitcnt vmcnt(8)\n\ts_barrier" ::: "memory");
  STAGE_T(3, 127 * 32);
  gemm_compute_tile(LB[0], wm, wn, fofs, acc);
  asm volatile("s_waitcnt vmcnt(8)\n\ts_barrier" ::: "memory");
  gemm_compute_tile(LB[1], wm, wn, fofs, acc);
  asm volatile("s_waitcnt vmcnt(4)\n\ts_barrier" ::: "memory");
  gemm_compute_tile(LB[2], wm, wn, fofs, acc);
  asm volatile("s_waitcnt vmcnt(0)\n\ts_barrier" ::: "memory");
  gemm_compute_tile(LB[3], wm, wn, fofs, acc);
#undef STAGE_T

  const int en = lane & 15;
  const int em = (lane >> 4) * 4;
#pragma unroll
  for (int i = 0; i < 4; ++i) {
#pragma unroll
    for (int j = 0; j < 4; ++j) {
      const int m0 = rb + wm + i * 16 + em;
      const int n = cb + wn + j * 16 + en;
      half_t h0 = (half_t)acc[i][j][0];
      half_t h1 = (half_t)acc[i][j][1];
      half_t h2 = (half_t)acc[i][j][2];
      half_t h3 = (half_t)acc[i][j][3];
      if (Ct) {
        f16x4 t4 = {h0, h1, h2, h3};
        *(f16x4*)&Ct[(size_t)n * LDT + m0] = t4;
      }
      Cn[(size_t)(m0 + 0) * NPAD + n] = h0;
      Cn[(size_t)(m0 + 1) * NPAD + n] = h1;
      Cn[(size_t)(m0 + 2) * NPAD + n] = h2;
      Cn[(size_t)(m0 + 3) * NPAD + n] = h3;
    }
  }
}

// ---------------------------------------------------------------------------
// R18: coalesced transpose Cbn (node-major) -> Cbt (col-major). 64x64 LDS
// tiles, both global sides coalesced.
// ---------------------------------------------------------------------------
__global__ __launch_bounds__(256) void k_tr(const half_t* __restrict__ Cbn,
                                            half_t* __restrict__ Ct) {
  __shared__ half_t T[64][69];
  const int tid = threadIdx.x;
  const int cb = blockIdx.x * 64;   // col base (0..2048)
  const int mb = blockIdx.y * 64;   // node base
  const int c4 = (tid & 15) * 4;
  const int r0 = tid >> 4;
#pragma unroll
  for (int it = 0; it < 4; ++it) {
    const int r = r0 + it * 16;
    f16x4 v = *(const f16x4*)&Cbn[(size_t)(mb + r) * NPAD + cb + c4];
    T[r][c4 + 0] = v[0];
    T[r][c4 + 1] = v[1];
    T[r][c4 + 2] = v[2];
    T[r][c4 + 3] = v[3];
  }
  __syncthreads();
#pragma unroll
  for (int it = 0; it < 4; ++it) {
    const int c2 = r0 + it * 16;     // col within tile
    const int m4 = c4;               // node within tile
    f16x4 v = {T[m4 + 0][c2], T[m4 + 1][c2], T[m4 + 2][c2], T[m4 + 3][c2]};
    *(f16x4*)&Ct[(size_t)(cb + c2) * LDT + mb + m4] = v;
  }
}

// ---------------------------------------------------------------------------
// WT2: d-pair-packed fp16 pool, L2-resident (R15 ki = k*KSEC + i layout).
// ---------------------------------------------------------------------------
__global__ __launch_bounds__(256) void k_wgt2(const float* __restrict__ Wg,
                                              const float* __restrict__ Wu,
                                              unsigned* __restrict__ WT2) {
  const int r = blockIdx.x * 256 + threadIdx.x;
  if (r >= WGT2_R) return;
  const float* pool;
  int o, ki, ostr;
  if (r < WROW_G) { o = r / KILD; ki = r % KILD; pool = Wg; ostr = 128; }
  else { int r2 = r - WROW_G; o = r2 / KILD; ki = r2 % KILD; pool = Wu; ostr = 64; }
  const int k = ki / KSEC;
  const int i = ki - k * KSEC;
#pragma unroll
  for (int dp = 0; dp < 5; ++dp) {
    u32h2 v; v.h = f16x2{(half_t)0.f, (half_t)0.f};
    if (ki < KI_REAL && i < CI) {
      v.h[0] = (half_t)pool[(((size_t)(2 * dp) * KSUP + k) * CI + i) * ostr + o];
      v.h[1] = (half_t)pool[(((size_t)(2 * dp + 1) * KSUP + k) * CI + i) * ostr + o];
    }
    WT2[(size_t)dp * WGT2_R + r] = v.u;
  }
}

// ---------------------------------------------------------------------------
// Stage xg for one node into LDS (R15 vectorized).
// ---------------------------------------------------------------------------
__device__ __forceinline__ void stage_xg(const half_t* __restrict__ v0r,
                                         const half_t* __restrict__ g1r,
                                         const half_t* __restrict__ g2r,
                                         half_t* __restrict__ xg, int tid, int nthr) {
  for (int w = tid; w < 32 * 9; w += nthr) {
    const int b = w / 9;
    const int oct = w - b * 9;
    half_t* row = xg + b * KILD;
    const half_t* pv = v0r + b * CI;
    const half_t* pg1 = g1r + b * CI;
    const half_t* pg2 = g2r + b * CI;
    if (oct < 8) {
      const f16x8 v0 = loadu8h(pv + oct * 8);
      const f16x8 g1 = loadu8h(pg1 + oct * 8);
      const f16x8 g2 = loadu8h(pg2 + oct * 8);
      const f16x8 x2 = g2 + g2 - v0;
      *(f16x8*)&row[oct * 8] = v0;
      *(f16x8*)&row[KSEC + oct * 8] = g1;
      *(f16x8*)&row[2 * KSEC + oct * 8] = x2;
    } else {
      u32h2 tv, tg1, tg2;
      tv.u = *(const unsigned*)(pv + 64);
      tg1.u = *(const unsigned*)(pg1 + 64);
      tg2.u = *(const unsigned*)(pg2 + 64);
      f16x8 v0 = {}, g1 = {}, x2 = {};
      v0[0] = tv.h[0]; v0[1] = tv.h[1];
      g1[0] = tg1.h[0]; g1[1] = tg1.h[1];
      x2[0] = tg2.h[0] + tg2.h[0] - tv.h[0];
      x2[1] = tg2.h[1] + tg2.h[1] - tv.h[1];
      *(f16x8*)&row[64] = v0;
      *(f16x8*)&row[KSEC + 64] = g1;
      *(f16x8*)&row[2 * KSEC + 64] = x2;
    }
  }
  for (int w = tid; w < 32 * 2; w += nthr) {
    const f16x8 z = {};
    *(f16x8*)&xg[(w >> 1) * KILD + KI_REAL + (w & 1) * 8] = z;
  }
}

// ---------------------------------------------------------------------------
// Gate transform: block = 2 nodes, 512 threads. R18 write layout (Cbn only,
// Rb node-major).
// ---------------------------------------------------------------------------
__global__ __launch_bounds__(512) void k_gate_t(const half_t* __restrict__ Vn,
                                                const half_t* __restrict__ G1n,
                                                const half_t* __restrict__ G2n,
                                                const unsigned* __restrict__ WT2,
                                                const float* __restrict__ E,
                                                const float* __restrict__ bg,
                                                const float* __restrict__ H,
                                                half_t* __restrict__ Cbn,
                                                half_t* __restrict__ Rb) {
  const int n0 = blockIdx.x * 2;
  const int tid = threadIdx.x;
  const int lane = tid & 63;
  const int wave = tid >> 6;
  __shared__ half_t Wl[2][OCH];
  __shared__ half_t xg[2][OCH];
  __shared__ float biasl[2][128];

  f16x2 e2p0[5], e2p1[5];
#pragma unroll
  for (int dp = 0; dp < 5; ++dp) {
    e2p0[dp][0] = (half_t)E[n0 * D_EMB + 2 * dp];
    e2p0[dp][1] = (half_t)E[n0 * D_EMB + 2 * dp + 1];
    e2p1[dp][0] = (half_t)E[(n0 + 1) * D_EMB + 2 * dp];
    e2p1[dp][1] = (half_t)E[(n0 + 1) * D_EMB + 2 * dp + 1];
  }

  if (tid < 256) {
    const int nn = tid >> 7;
    const int o = tid & 127;
    float s = 0.f;
#pragma unroll
    for (int d = 0; d < D_EMB; ++d) s += E[(n0 + nn) * D_EMB + d] * bg[d * 128 + o];
    biasl[nn][o] = s;
  }
  stage_xg(Vn + (size_t)n0 * NPAD, G1n + (size_t)n0 * NPAD, G2n + (size_t)n0 * NPAD, xg[0], tid, 512);
  stage_xg(Vn + (size_t)(n0 + 1) * NPAD, G1n + (size_t)(n0 + 1) * NPAD, G2n + (size_t)(n0 + 1) * NPAD, xg[1], tid, 512);

  const int fr = lane & 15;
  const int fk = (lane >> 4) * 8;
  const int en = lane & 15;
  const int em = (lane >> 4) * 4;
  const int node = wave & 1;
  const int ot = (wave >> 1) & 1;
  const int bh = wave >> 2;
  const int nn = n0 + node;

#pragma unroll
  for (int p = 0; p < 4; ++p) {
    if (p > 0) __syncthreads();
    for (int base = tid * 8; base < OCH; base += 4096) {
      float a0[8] = {}, a1[8] = {};
#pragma unroll
      for (int dp = 0; dp < 5; ++dp) {
        const unsigned* wrow = WT2 + (size_t)dp * WGT2_R + p * OCH + base;
        uint4 wa = *(const uint4*)wrow;
        uint4 wb = *(const uint4*)(wrow + 4);
        u32h2 c0, c1, c2, c3;
        c0.u = wa.x; c1.u = wa.y; c2.u = wa.z; c3.u = wa.w;
        a0[0] = __builtin_amdgcn_fdot2(c0.h, e2p0[dp], a0[0], false);
        a0[1] = __builtin_amdgcn_fdot2(c1.h, e2p0[dp], a0[1], false);
        a0[2] = __builtin_amdgcn_fdot2(c2.h, e2p0[dp], a0[2], false);
        a0[3] = __builtin_amdgcn_fdot2(c3.h, e2p0[dp], a0[3], false);
        a1[0] = __builtin_amdgcn_fdot2(c0.h, e2p1[dp], a1[0], false);
        a1[1] = __builtin_amdgcn_fdot2(c1.h, e2p1[dp], a1[1], false);
        a1[2] = __builtin_amdgcn_fdot2(c2.h, e2p1[dp], a1[2], false);
        a1[3] = __builtin_amdgcn_fdot2(c3.h, e2p1[dp], a1[3], false);
        c0.u = wb.x; c1.u = wb.y; c2.u = wb.z; c3.u = wb.w;
        a0[4] = __builtin_amdgcn_fdot2(c0.h, e2p0[dp], a0[4], false);
        a0[5] = __builtin_amdgcn_fdot2(c1.h, e2p0[dp], a0[5], false);
        a0[6] = __builtin_amdgcn_fdot2(c2.h, e2p0[dp], a0[6], false);
        a0[7] = __builtin_amdgcn_fdot2(c3.h, e2p0[dp], a0[7], false);
        a1[4] = __builtin_amdgcn_fdot2(c0.h, e2p1[dp], a1[4], false);
        a1[5] = __builtin_amdgcn_fdot2(c1.h, e2p1[dp], a1[5], false);
        a1[6] = __builtin_amdgcn_fdot2(c2.h, e2p1[dp], a1[6], false);
        a1[7] = __builtin_amdgcn_fdot2(c3.h, e2p1[dp], a1[7], false);
      }
      f16x8 w0, w1;
#pragma unroll
      for (int e = 0; e < 8; ++e) { w0[e] = (half_t)a0[e]; w1[e] = (half_t)a1[e]; }
      *(f16x8*)&Wl[0][base] = w0;
      *(f16x8*)&Wl[1][base] = w1;
    }
    __syncthreads();

    f32x4 acc2 = {};
#pragma unroll
    for (int ks = 0; ks < 7; ++ks) {
      const f16x8 a0 = *(const f16x8*)&xg[node][(bh * 16 + fr) * KILD + ks * 32 + fk];
      const f16x8 b0 = *(const f16x8*)&Wl[node][(ot * 16 + fr) * KILD + ks * 32 + fk];
      acc2 = __builtin_amdgcn_mfma_f32_16x16x32_f16(a0, b0, acc2, 0, 0, 0);
    }
    const int o_g = p * 32 + ot * 16 + en;
    const float bo = biasl[node][o_g];
#pragma unroll
    for (int r = 0; r < 4; ++r) {
      const int b = bh * 16 + em + r;
      const float s = fast_sigmoid(acc2[r] + bo);
      if (p < 2) {
        const float hv = H[((size_t)b * N_NODES + nn) * COUT + o_g];
        const half_t z = (half_t)(s * hv);
        Cbn[(size_t)nn * NPAD + b * CI + CIN + o_g] = z;
      } else {
        Rb[(size_t)nn * 2048 + b * COUT + (o_g - 64)] = (half_t)s;
      }
    }
  }
}

// ---------------------------------------------------------------------------
// Update transform: block = 2 nodes, 512 threads. Rb read node-major.
// ---------------------------------------------------------------------------
__global__ __launch_bounds__(512) void k_update_t(const half_t* __restrict__ Cbn,
                                                  const half_t* __restrict__ G1n,
                                                  const half_t* __restrict__ G2n,
                                                  const unsigned* __restrict__ WT2,
                                                  const float* __restrict__ E,
                                                  const float* __restrict__ bu,
                                                  const float* __restrict__ H,
                                                  const half_t* __restrict__ Rb,
                                                  float* __restrict__ Out) {
  const int n0 = blockIdx.x * 2;
  const int tid = threadIdx.x;
  const int lane = tid & 63;
  const int wave = tid >> 6;
  __shared__ half_t Wl[2][OCH];
  __shared__ half_t xg[2][OCH];
  __shared__ float biasl[2][64];

  f16x2 e2p0[5], e2p1[5];
#pragma unroll
  for (int dp = 0; dp < 5; ++dp) {
    e2p0[dp][0] = (half_t)E[n0 * D_EMB + 2 * dp];
    e2p0[dp][1] = (half_t)E[n0 * D_EMB + 2 * dp + 1];
    e2p1[dp][0] = (half_t)E[(n0 + 1) * D_EMB + 2 * dp];
    e2p1[dp][1] = (half_t)E[(n0 + 1) * D_EMB + 2 * dp + 1];
  }

  if (tid < 128) {
    const int nn = tid >> 6;
    const int o = tid & 63;
    float s = 0.f;
#pragma unroll
    for (int d = 0; d < D_EMB; ++d) s += E[(n0 + nn) * D_EMB + d] * bu[d * COUT + o];
    biasl[nn][o] = s;
  }
  stage_xg(Cbn + (size_t)n0 * NPAD, G1n + (size_t)n0 * NPAD, G2n + (size_t)n0 * NPAD, xg[0], tid, 512);
  stage_xg(Cbn + (size_t)(n0 + 1) * NPAD, G1n + (size_t)(n0 + 1) * NPAD, G2n + (size_t)(n0 + 1) * NPAD, xg[1], tid, 512);

  const int fr = lane & 15;
  const int fk = (lane >> 4) * 8;
  const int en = lane & 15;
  const int em = (lane >> 4) * 4;
  const int node = wave & 1;
  const int ot = (wave >> 1) & 1;
  const int bh = wave >> 2;
  const int nn = n0 + node;

#pragma unroll
  for (int p = 0; p < 2; ++p) {
    if (p > 0) __syncthreads();
    for (int base = tid * 8; base < OCH; base += 4096) {
      float a0[8] = {}, a1[8] = {};
#pragma unroll
      for (int dp = 0; dp < 5; ++dp) {
        const unsigned* wrow = WT2 + (size_t)dp * WGT2_R + WROW_G + p * OCH + base;
        uint4 wa = *(const uint4*)wrow;
        uint4 wb = *(const uint4*)(wrow + 4);
        u32h2 c0, c1, c2, c3;
        c0.u = wa.x; c1.u = wa.y; c2.u = wa.z; c3.u = wa.w;
        a0[0] = __builtin_amdgcn_fdot2(c0.h, e2p0[dp], a0[0], false);
        a0[1] = __builtin_amdgcn_fdot2(c1.h, e2p0[dp], a0[1], false);
        a0[2] = __builtin_amdgcn_fdot2(c2.h, e2p0[dp], a0[2], false);
        a0[3] = __builtin_amdgcn_fdot2(c3.h, e2p0[dp], a0[3], false);
        a1[0] = __builtin_amdgcn_fdot2(c0.h, e2p1[dp], a1[0], false);
        a1[1] = __builtin_amdgcn_fdot2(c1.h, e2p1[dp], a1[1], false);
        a1[2] = __builtin_amdgcn_fdot2(c2.h, e2p1[dp], a1[2], false);
        a1[3] = __builtin_amdgcn_fdot2(c3.h, e2p1[dp], a1[3], false);
        c0.u = wb.x; c1.u = wb.y; c2.u = wb.z; c3.u = wb.w;
        a0[4] = __builtin_amdgcn_fdot2(c0.h, e2p0[dp], a0[4], false);
        a0[5] = __builtin_amdgcn_fdot2(c1.h, e2p0[dp], a0[5], false);
        a0[6] = __builtin_amdgcn_fdot2(c2.h, e2p0[dp], a0[6], false);
        a0[7] = __builtin_amdgcn_fdot2(c3.h, e2p0[dp], a0[7], false);
        a1[4] = __builtin_amdgcn_fdot2(c0.h, e2p1[dp], a1[4], false);
        a1[5] = __builtin_amdgcn_fdot2(c1.h, e2p1[dp], a1[5], false);
        a1[6] = __builtin_amdgcn_fdot2(c2.h, e2p1[dp], a1[6], false);
        a1[7] = __builtin_amdgcn_fdot2(c3.h, e2p1[dp], a1[7], false);
      }
      f16x8 w0, w1;
#pragma unroll
      for (int e = 0; e < 8; ++e) { w0[e] = (half_t)a0[e]; w1[e] = (half_t)a1[e]; }
      *(f16x8*)&Wl[0][base] = w0;
      *(f16x8*)&Wl[1][base] = w1;
    }
    __syncthreads();

    f32x4 acc2 = {};
#pragma unroll
    for (int ks = 0; ks < 7; ++ks) {
      const f16x8 a0 = *(const f16x8*)&xg[node][(bh * 16 + fr) * KILD + ks * 32 + fk];
      const f16x8 b0 = *(const f16x8*)&Wl[node][(ot * 16 + fr) * KILD + ks * 32 + fk];
      acc2 = __builtin_amdgcn_mfma_f32_16x16x32_f16(a0, b0, acc2, 0, 0, 0);
    }
    const int o = p * 32 + ot * 16 + en;
    const float bo = biasl[node][o];
#pragma unroll
    for (int r = 0; r < 4; ++r) {
      const int b = bh * 16 + em + r;
      const float hc = fast_tanh(acc2[r] + bo);
      const float hv = H[((size_t)b * N_NODES + nn) * COUT + o];
      const float rr = (float)Rb[(size_t)nn * 2048 + b * COUT + o];
      Out[((size_t)b * N_NODES + nn) * COUT + o] = rr * hv + (1.f - rr) * hc;
    }
  }
}

// ---------------------------------------------------------------------------
extern "C" void kernel_launch(void* const* d_in, const int* in_sizes, int n_in,
                              void* d_out, int out_size, void* d_ws, size_t ws_size,
                              hipStream_t stream) {
  const float* X  = (const float*)d_in[0];
  const float* H  = (const float*)d_in[1];
  const float* E  = (const float*)d_in[2];
  const float* Wg = (const float*)d_in[3];
  const float* bg = (const float*)d_in[4];
  const float* Wu = (const float*)d_in[5];
  const float* bu = (const float*)d_in[6];
  float* out = (float*)d_out;

  const size_t SZ_P = (size_t)N_NODES * N_NODES;
  const size_t SZ_M = (size_t)NPAD * LDT;
  half_t* Pb  = (half_t*)d_ws;
  half_t* Vt  = Pb + SZ_P;
  half_t* Vn  = Vt + SZ_M;
  half_t* G1t = Vn + SZ_M;
  half_t* G1n = G1t + SZ_M;
  half_t* G2n = G1n + SZ_M;
  half_t* Cbt = G2n + SZ_M;
  half_t* Cbn = Cbt + SZ_M;
  half_t* Rb  = Cbn + SZ_M;
  unsigned* WT2 = (unsigned*)(Rb + (size_t)BATCH * N_NODES * COUT);

  // 1. adjacency + inputs + packed pool
  k_softmax_p<<<N_NODES, 256, 0, stream>>>(E, Pb);
  {
    const size_t tot = (size_t)N_NODES * NCOLS;
    k_build_v0<<<(int)((tot + 255) / 256), 256, 0, stream>>>(X, H, Vt, Vn, Cbn);
  }
  k_wgt2<<<(WGT2_R + 255) / 256, 256, 0, stream>>>(Wg, Wu, WT2);

  const dim3 gg(17, 32);       // full-K GEMM grid
  const dim3 gt(33, 64);       // transpose grid (64x64 tiles over 2112x4096)

  // 2. gate propagation + transform
  k_gemm_f16<<<gg, 256, 0, stream>>>(Pb, Vt, G1n, G1t);
  k_gemm_f16<<<gg, 256, 0, stream>>>(Pb, G1t, G2n, nullptr);
  k_gate_t<<<N_NODES / 2, 512, 0, stream>>>(Vn, G1n, G2n, WT2, E, bg, H, Cbn, Rb);
  k_tr<<<gt, 256, 0, stream>>>(Cbn, Cbt);

  // 3. update propagation + transform + output
  k_gemm_f16<<<gg, 256, 0, stream>>>(Pb, Cbt, G1n, G1t);
  k_gemm_f16<<<gg, 256, 0, stream>>>(Pb, G1t, G2n, nullptr);
  k_update_t<<<N_NODES / 2, 512, 0, stream>>>(Cbn, G1n, G2n, WT2, E, bu, H, Rb, out);
}